// Round 1
// baseline (2170.895 us; speedup 1.0000x reference)
//
#include <hip/hip_runtime.h>
#include <math.h>

#define NB 4
#define ND 1024
#define NL 2048
#define NH 16
#define NDH 64
#define INV_SCALE 0.125f   // 1/sqrt(64)

typedef float f4 __attribute__((ext_vector_type(4)));

// ---------------------------------------------------------------------------
// GEMM: C[b, o, l] = sum_d W[o,d] * X[b,d,l]  (+ bias[o] if bias != nullptr)
// W: ND x ND row-major. X/C: per batch ND x NL row-major.
// grid: (NL/64, ND/64, NB), block 256 (ti=tid/16 -> o, tj=tid%16 -> l),
// each thread computes a 4x4 micro-tile.
// ---------------------------------------------------------------------------
__global__ __launch_bounds__(256) void gemm_f32(
    const float* __restrict__ W, const float* __restrict__ X,
    float* __restrict__ C, const float* __restrict__ bias)
{
    __shared__ float Ws[16][68];  // Ws[k][o]  (W transposed tile, +4 pad keeps 16B align)
    __shared__ float Xs[16][68];  // Xs[k][l]

    const int tid = threadIdx.x;
    const int ti = tid >> 4, tj = tid & 15;
    const int b  = blockIdx.z;
    const int o0 = blockIdx.y * 64;
    const int l0 = blockIdx.x * 64;

    const float* Xb = X + (size_t)b * ND * NL;
    float*       Cb = C + (size_t)b * ND * NL;

    float acc[4][4] = {};

    for (int k0 = 0; k0 < ND; k0 += 16) {
        // stage W tile 64(o) x 16(d) -> Ws[d][o]
        #pragma unroll
        for (int r = 0; r < 4; ++r) {
            int idx = tid + r * 256;            // 0..1023
            int o = idx >> 4, d = idx & 15;
            Ws[d][o] = W[(size_t)(o0 + o) * ND + (k0 + d)];
        }
        // stage X tile 16(d) x 64(l) -> Xs[d][l]
        #pragma unroll
        for (int r = 0; r < 4; ++r) {
            int idx = tid + r * 256;
            int d = idx >> 6, l = idx & 63;
            Xs[d][l] = Xb[(size_t)(k0 + d) * NL + (l0 + l)];
        }
        __syncthreads();
        #pragma unroll
        for (int kk = 0; kk < 16; ++kk) {
            f4 a = *(const f4*)&Ws[kk][ti * 4];
            f4 x = *(const f4*)&Xs[kk][tj * 4];
            #pragma unroll
            for (int p = 0; p < 4; ++p)
                #pragma unroll
                for (int q = 0; q < 4; ++q)
                    acc[p][q] += a[p] * x[q];
        }
        __syncthreads();
    }

    #pragma unroll
    for (int p = 0; p < 4; ++p) {
        int o = o0 + ti * 4 + p;
        float bv = bias ? bias[o] : 0.0f;
        f4 out;
        #pragma unroll
        for (int q = 0; q < 4; ++q) out[q] = acc[p][q] + bv;
        *(f4*)&Cb[(size_t)o * NL + l0 + tj * 4] = out;
    }
}

// ---------------------------------------------------------------------------
// Flash attention, fp32. One block per (b, h, 64-query tile).
// Q,K,V: laid out as (NB, ND, NL); head h occupies rows h*64..h*64+63.
// S[i][j] = sum_d Q[d,i]*K[d,j] * INV_SCALE ; P = softmax_j ; O[d,i] = sum_j P[i,j] V[d,j]
// O is written back over Q's storage (each block only reads its own Q range first).
// block 256: ti=tid/16, tj=tid%15.  S-phase: thread owns S[ti*4+p][tj*4+q].
// O-phase: thread owns O[d=ti*4+p][i=tj*4+q].
// ---------------------------------------------------------------------------
__global__ __launch_bounds__(256) void attn_f32(
    const float* __restrict__ Q, const float* __restrict__ K,
    const float* __restrict__ V, float* __restrict__ O)
{
    __shared__ float Qs[64][68];   // Qs[d][i], pre-scaled by 1/sqrt(Dh)
    __shared__ float Ks[64][68];   // Ks[d][j]
    __shared__ float Vt[64][68];   // Vt[j][d]
    __shared__ float Pt[64][68];   // Pt[j][i]
    __shared__ float m_s[64], l_s[64], alpha_s[64];

    const int tid = threadIdx.x;
    const int ti = tid >> 4, tj = tid & 15;
    const int i0 = blockIdx.x * 64;
    const int h  = blockIdx.y;
    const int b  = blockIdx.z;

    const size_t head_off = ((size_t)b * ND + (size_t)h * NDH) * NL;
    const float* Qg = Q + head_off;
    const float* Kg = K + head_off;
    const float* Vg = V + head_off;
    float*       Og = O + head_off;

    // stage Q tile (64 d x 64 i), scaled
    #pragma unroll
    for (int r = 0; r < 16; ++r) {
        int idx = tid + r * 256;          // 0..4095
        int d = idx >> 6, i = idx & 63;
        Qs[d][i] = Qg[(size_t)d * NL + i0 + i] * INV_SCALE;
    }
    if (tid < 64) { m_s[tid] = -INFINITY; l_s[tid] = 0.0f; }

    float o_acc[4][4] = {};

    for (int j0 = 0; j0 < NL; j0 += 64) {
        __syncthreads();   // previous O-update done; safe to restage K/V
        // stage K tile (64 d x 64 j) -> Ks[d][j]; V tile -> Vt[j][d]
        #pragma unroll
        for (int r = 0; r < 16; ++r) {
            int idx = tid + r * 256;
            int d = idx >> 6, j = idx & 63;
            Ks[d][j] = Kg[(size_t)d * NL + j0 + j];
            Vt[j][d] = Vg[(size_t)d * NL + j0 + j];
        }
        __syncthreads();

        // S = Q^T K  (scaled) : thread owns s[p][q], i=ti*4+p, j=tj*4+q
        float s[4][4] = {};
        #pragma unroll 8
        for (int d = 0; d < 64; ++d) {
            f4 qv = *(const f4*)&Qs[d][ti * 4];
            f4 kv = *(const f4*)&Ks[d][tj * 4];
            #pragma unroll
            for (int p = 0; p < 4; ++p)
                #pragma unroll
                for (int q = 0; q < 4; ++q)
                    s[p][q] += qv[p] * kv[q];
        }

        // row max over j (reduce across tj group of 16 lanes)
        float rm[4];
        #pragma unroll
        for (int p = 0; p < 4; ++p) {
            float v = fmaxf(fmaxf(s[p][0], s[p][1]), fmaxf(s[p][2], s[p][3]));
            #pragma unroll
            for (int msk = 1; msk < 16; msk <<= 1)
                v = fmaxf(v, __shfl_xor(v, msk, 16));
            rm[p] = v;
        }
        if (tj == 0) {
            #pragma unroll
            for (int p = 0; p < 4; ++p) {
                int i = ti * 4 + p;
                float mo = m_s[i];
                float mn = fmaxf(mo, rm[p]);
                alpha_s[i] = expf(mo - mn);
                m_s[i] = mn;
            }
        }
        __syncthreads();   // m_s / alpha_s ready

        // P = exp(S - m), write transposed; row-sum
        float rs[4];
        #pragma unroll
        for (int p = 0; p < 4; ++p) {
            int i = ti * 4 + p;
            float mn = m_s[i];
            float sum = 0.0f;
            #pragma unroll
            for (int q = 0; q < 4; ++q) {
                float pv = expf(s[p][q] - mn);
                Pt[tj * 4 + q][i] = pv;
                sum += pv;
            }
            #pragma unroll
            for (int msk = 1; msk < 16; msk <<= 1)
                sum += __shfl_xor(sum, msk, 16);
            rs[p] = sum;
        }
        if (tj == 0) {
            #pragma unroll
            for (int p = 0; p < 4; ++p) {
                int i = ti * 4 + p;
                l_s[i] = alpha_s[i] * l_s[i] + rs[p];
            }
        }
        __syncthreads();   // Pt, l_s ready

        // O update: o[p][q] (d=ti*4+p, i=tj*4+q)
        float al[4];
        #pragma unroll
        for (int q = 0; q < 4; ++q) al[q] = alpha_s[tj * 4 + q];
        #pragma unroll
        for (int p = 0; p < 4; ++p)
            #pragma unroll
            for (int q = 0; q < 4; ++q)
                o_acc[p][q] *= al[q];
        #pragma unroll 8
        for (int j = 0; j < 64; ++j) {
            f4 pv = *(const f4*)&Pt[j][tj * 4];
            f4 vv = *(const f4*)&Vt[j][ti * 4];
            #pragma unroll
            for (int p = 0; p < 4; ++p)
                #pragma unroll
                for (int q = 0; q < 4; ++q)
                    o_acc[p][q] += vv[p] * pv[q];
        }
    }
    __syncthreads();   // l_s final

    float linv[4];
    #pragma unroll
    for (int q = 0; q < 4; ++q) linv[q] = 1.0f / l_s[tj * 4 + q];

    #pragma unroll
    for (int p = 0; p < 4; ++p) {
        int d = ti * 4 + p;
        f4 out;
        #pragma unroll
        for (int q = 0; q < 4; ++q) out[q] = o_acc[p][q] * linv[q];
        *(f4*)&Og[(size_t)d * NL + i0 + tj * 4] = out;
    }
}

// ---------------------------------------------------------------------------
extern "C" void kernel_launch(void* const* d_in, const int* in_sizes, int n_in,
                              void* d_out, int out_size, void* d_ws, size_t ws_size,
                              hipStream_t stream) {
    const float* x  = (const float*)d_in[0];
    const float* wq = (const float*)d_in[1];
    const float* wk = (const float*)d_in[2];
    const float* wv = (const float*)d_in[3];
    const float* wo = (const float*)d_in[4];
    const float* bo = (const float*)d_in[5];
    float* out = (float*)d_out;

    const size_t elems = (size_t)NB * ND * NL;   // 8,388,608
    float* qb = (float*)d_ws;
    float* kb = qb + elems;
    float* vb = kb + elems;

    dim3 gb(NL / 64, ND / 64, NB);   // 32 x 16 x 4
    dim3 tb(256);
    hipLaunchKernelGGL(gemm_f32, gb, tb, 0, stream, wq, x, qb, nullptr);
    hipLaunchKernelGGL(gemm_f32, gb, tb, 0, stream, wk, x, kb, nullptr);
    hipLaunchKernelGGL(gemm_f32, gb, tb, 0, stream, wv, x, vb, nullptr);

    dim3 ga(NL / 64, NH, NB);        // 32 x 16 x 4
    hipLaunchKernelGGL(attn_f32, ga, tb, 0, stream, qb, kb, vb, qb);

    hipLaunchKernelGGL(gemm_f32, gb, tb, 0, stream, wo, qb, out, bo);
}

// Round 2
// 647.408 us; speedup vs baseline: 3.3532x; 3.3532x over previous
//
#include <hip/hip_runtime.h>
#include <math.h>

#define NB 4
#define ND 1024
#define NL 2048
#define NH 16
#define NDH 64

typedef float f4 __attribute__((ext_vector_type(4)));
typedef float f32x4 __attribute__((ext_vector_type(4)));
typedef short bf16x8 __attribute__((ext_vector_type(8)));
typedef unsigned short u16;
typedef u16 u16x4 __attribute__((ext_vector_type(4)));

#define MFMA16 __builtin_amdgcn_mfma_f32_16x16x32_bf16

__device__ __forceinline__ u16 bf16_rne(float f) {
  unsigned u = __float_as_uint(f);
  u += 0x7fffu + ((u >> 16) & 1u);
  return (u16)(u >> 16);
}
__device__ __forceinline__ float bf16_to_f(u16 h) {
  return __uint_as_float(((unsigned)h) << 16);
}
__device__ __forceinline__ void gll16(const void* g, void* l) {
  __builtin_amdgcn_global_load_lds(
      (const __attribute__((address_space(1))) void*)g,
      (__attribute__((address_space(3))) void*)l, 16, 0, 0);
}

// ---------------------------------------------------------------------------
// Prepass: X [b][d][l] fp32 -> Xt hi/lo bf16 [b][l][d] (transpose via LDS)
// ---------------------------------------------------------------------------
__global__ __launch_bounds__(256) void prep_x(const float* __restrict__ X,
                                              u16* __restrict__ Xhi,
                                              u16* __restrict__ Xlo) {
  __shared__ float t[64][65];
  const int tid = threadIdx.x;
  const int l0 = blockIdx.x * 64, d0 = blockIdx.y * 64, b = blockIdx.z;
  const float* Xb = X + ((size_t)b * ND + d0) * NL + l0;
#pragma unroll
  for (int r = 0; r < 16; ++r) {
    int idx = tid + r * 256;
    int d = idx >> 6, l = idx & 63;
    t[d][l] = Xb[(size_t)d * NL + l];
  }
  __syncthreads();
#pragma unroll
  for (int r = 0; r < 16; ++r) {
    int idx = tid + r * 256;
    int li = idx >> 6, dd = idx & 63;
    float v = t[dd][li];
    u16 hh = bf16_rne(v);
    size_t o = ((size_t)b * NL + l0 + li) * ND + d0 + dd;
    Xhi[o] = hh;
    Xlo[o] = bf16_rne(v - bf16_to_f(hh));
  }
}

// ---------------------------------------------------------------------------
// Prepass: W [o][d] fp32 -> hi/lo bf16 (no transpose), 4 elems/thread
// ---------------------------------------------------------------------------
__global__ __launch_bounds__(256) void prep_w(const float* __restrict__ W,
                                              u16* __restrict__ Whi,
                                              u16* __restrict__ Wlo) {
  int i = blockIdx.x * 256 + threadIdx.x;  // grid sized exactly
  f4 v = ((const f4*)W)[i];
  u16x4 h, l;
#pragma unroll
  for (int k = 0; k < 4; ++k) {
    h[k] = bf16_rne(v[k]);
    l[k] = bf16_rne(v[k] - bf16_to_f(h[k]));
  }
  ((u16x4*)Whi)[i] = h;
  ((u16x4*)Wlo)[i] = l;
}

// ---------------------------------------------------------------------------
// Split-bf16 MFMA GEMM: C[b,o,l] = sum_d W[o,d] * X[b,l,d]   (X given l-major)
// 128x128 tile, BK=32, double-buffered LDS, global_load_lds(16B) staging.
// LDS tile layout: pair-interleaved XOR swizzle -> conflict-free ds_read_b128:
//   phys(r,s16) = (r>>1)*128 + ((((r&1)<<2)|s16) ^ ((r>>1)&7))*16
// MODE 0: fp32 + bias out [b][o][l]
// MODE 1: bf16 hi/lo transposed out [b][l][o], with scale (exact for 2^-k)
// MODE 2: bf16 hi/lo natural out [b][o][l]
// ---------------------------------------------------------------------------
template <int MODE>
__global__ __launch_bounds__(256) void gemm_split(
    const u16* __restrict__ Ahi, const u16* __restrict__ Alo,
    const u16* __restrict__ Bhi, const u16* __restrict__ Blo,
    float* __restrict__ Cf, const float* __restrict__ bias,
    u16* __restrict__ Chi, u16* __restrict__ Clo, float scale) {
  __shared__ char smem[65536];
  const int tid = threadIdx.x;
  const int lane = tid & 63, wv = tid >> 6;
  const int l0 = blockIdx.x * 128, o0 = blockIdx.y * 128, b = blockIdx.z;
  const int wo = (wv >> 1) * 64, wl = (wv & 1) * 64;

  // staging source map (inverse of phys layout); issue q adds 64 rows
  const int pr = tid >> 3;
  const int e = (tid & 7) ^ (pr & 7);
  const int r_src = pr * 2 + (e >> 2);
  const int s_src = e & 3;
  const char* gAh = (const char*)(Ahi + (size_t)(o0 + r_src) * ND) + s_src * 16;
  const char* gAl = (const char*)(Alo + (size_t)(o0 + r_src) * ND) + s_src * 16;
  const char* gBh = (const char*)(Bhi + ((size_t)b * NL + l0 + r_src) * ND) + s_src * 16;
  const char* gBl = (const char*)(Blo + ((size_t)b * NL + l0 + r_src) * ND) + s_src * 16;
  const int QROW = 64 * ND * 2;

  // fragment read offsets (per-lane constant swizzle)
  const int fswz = ((((lane & 1) << 2) | (lane >> 4)) ^ ((lane >> 1) & 7)) << 4;
  int offA[4], offB[4];
#pragma unroll
  for (int f = 0; f < 4; ++f) {
    offA[f] = ((wo + 16 * f + (lane & 15)) >> 1) * 128 + fswz;
    offB[f] = ((wl + 16 * f + (lane & 15)) >> 1) * 128 + fswz;
  }

  f32x4 acc[4][4];
#pragma unroll
  for (int mf = 0; mf < 4; ++mf)
#pragma unroll
    for (int nf = 0; nf < 4; ++nf) acc[mf][nf] = 0.0f;

  auto stage = [&](char* bb, int kbyte) {
    char* d = bb + wv * 1024;
    gll16(gAh + kbyte, d);
    gll16(gAh + kbyte + QROW, d + 4096);
    gll16(gAl + kbyte, d + 8192);
    gll16(gAl + kbyte + QROW, d + 12288);
    gll16(gBh + kbyte, d + 16384);
    gll16(gBh + kbyte + QROW, d + 20480);
    gll16(gBl + kbyte, d + 24576);
    gll16(gBl + kbyte + QROW, d + 28672);
  };

  stage(smem, 0);
  int cur = 0;
  for (int ks = 0; ks < ND / 32; ++ks) {
    __syncthreads();
    if (ks + 1 < ND / 32) stage(smem + (cur ^ 1) * 32768, (ks + 1) * 64);
    const char* sb = smem + cur * 32768;
    bf16x8 ah[4], al[4], bh[4], bl[4];
#pragma unroll
    for (int f = 0; f < 4; ++f) {
      ah[f] = *(const bf16x8*)(sb + offA[f]);
      al[f] = *(const bf16x8*)(sb + 8192 + offA[f]);
      bh[f] = *(const bf16x8*)(sb + 16384 + offB[f]);
      bl[f] = *(const bf16x8*)(sb + 24576 + offB[f]);
    }
#pragma unroll
    for (int mf = 0; mf < 4; ++mf)
#pragma unroll
      for (int nf = 0; nf < 4; ++nf) {
        acc[mf][nf] = MFMA16(ah[mf], bh[nf], acc[mf][nf], 0, 0, 0);
        acc[mf][nf] = MFMA16(ah[mf], bl[nf], acc[mf][nf], 0, 0, 0);
        acc[mf][nf] = MFMA16(al[mf], bh[nf], acc[mf][nf], 0, 0, 0);
      }
    cur ^= 1;
  }

  const int col = lane & 15, row4 = (lane >> 4) * 4;
  if constexpr (MODE == 0) {
    const size_t cb = (size_t)b * ND * NL;
#pragma unroll
    for (int mf = 0; mf < 4; ++mf)
#pragma unroll
      for (int rg = 0; rg < 4; ++rg) {
        int o = o0 + wo + 16 * mf + row4 + rg;
        float bv = bias[o];
        float* crow = Cf + cb + (size_t)o * NL + l0 + wl + col;
#pragma unroll
        for (int nf = 0; nf < 4; ++nf) crow[16 * nf] = acc[mf][nf][rg] + bv;
      }
  } else if constexpr (MODE == 1) {
#pragma unroll
    for (int nf = 0; nf < 4; ++nf) {
      size_t lrow = ((size_t)b * NL + l0 + wl + 16 * nf + col) * ND + o0 + wo;
#pragma unroll
      for (int mf = 0; mf < 4; ++mf) {
        u16x4 h, l;
#pragma unroll
        for (int rg = 0; rg < 4; ++rg) {
          float v = acc[mf][nf][rg] * scale;
          h[rg] = bf16_rne(v);
          l[rg] = bf16_rne(v - bf16_to_f(h[rg]));
        }
        *(u16x4*)(Chi + lrow + 16 * mf + row4) = h;
        *(u16x4*)(Clo + lrow + 16 * mf + row4) = l;
      }
    }
  } else {
    const size_t cb = (size_t)b * ND * NL;
#pragma unroll
    for (int mf = 0; mf < 4; ++mf)
#pragma unroll
      for (int rg = 0; rg < 4; ++rg) {
        int o = o0 + wo + 16 * mf + row4 + rg;
        u16* hrow = Chi + cb + (size_t)o * NL + l0 + wl + col;
        u16* lrow2 = Clo + cb + (size_t)o * NL + l0 + wl + col;
#pragma unroll
        for (int nf = 0; nf < 4; ++nf) {
          float v = acc[mf][nf][rg];
          u16 hh = bf16_rne(v);
          hrow[16 * nf] = hh;
          lrow2[16 * nf] = bf16_rne(v - bf16_to_f(hh));
        }
      }
  }
}

// ---------------------------------------------------------------------------
// Flash attention, split-bf16 MFMA. Block = 4 waves x 32 query rows = 128 i.
// Q/K transposed bf16 hi/lo [b][l][o] (Q pre-scaled by 1/8); V natural [b][o][l].
// KVBLK=64, K/V double-buffered (row=128B, (r&7) slot-XOR swizzle).
// P routed via swizzled LDS (bf16 hi) -> PV A-operand. O -> [b][l][o] hi/lo.
// ---------------------------------------------------------------------------
__global__ __launch_bounds__(256) void attn_mfma(
    const u16* __restrict__ Qh, const u16* __restrict__ Ql,
    const u16* __restrict__ Kh, const u16* __restrict__ Kl,
    const u16* __restrict__ Vh, const u16* __restrict__ Vl,
    u16* __restrict__ Oh, u16* __restrict__ Ol) {
  __shared__ char smem[81920];  // 2x32KB K/V dbuf + 16KB P
  const int tid = threadIdx.x, lane = tid & 63, wv = tid >> 6;
  const int i0 = blockIdx.x * 128, h = blockIdx.y, b = blockIdx.z;
  const int iw = i0 + wv * 32;

  // Q fragments in registers (A-operand: i = lane&15 row, d = (lane>>4)*8+k)
  bf16x8 qh[2][2], ql[2][2];
  {
    const int il = lane & 15, dg = (lane >> 4) * 8;
#pragma unroll
    for (int mf = 0; mf < 2; ++mf) {
      size_t rowq = ((size_t)b * NL + iw + 16 * mf + il) * ND + h * NDH + dg;
#pragma unroll
      for (int ks = 0; ks < 2; ++ks) {
        qh[mf][ks] = *(const bf16x8*)(Qh + rowq + ks * 32);
        ql[mf][ks] = *(const bf16x8*)(Ql + rowq + ks * 32);
      }
    }
  }

  // staging map: tiles 64 rows x 128B, slot XOR (r&7)
  const int r0 = tid >> 3;
  const int swz0 = ((tid & 7) ^ (r0 & 7)) << 4;
  const char* gKh = (const char*)(Kh + ((size_t)b * NL + r0) * ND + h * NDH) + swz0;
  const char* gKl = (const char*)(Kl + ((size_t)b * NL + r0) * ND + h * NDH) + swz0;
  const char* gVh = (const char*)(Vh + ((size_t)b * ND + h * NDH + r0) * NL) + swz0;
  const char* gVl = (const char*)(Vl + ((size_t)b * ND + h * NDH + r0) * NL) + swz0;
  const int RSK = 32 * ND * 2, RSV = 32 * NL * 2;

  auto stage = [&](char* bb, int jt) {
    char* d = bb + wv * 1024;
    int ka = jt * (64 * ND * 2);
    int va = jt * 128;
    gll16(gKh + ka, d);
    gll16(gKh + ka + RSK, d + 4096);
    gll16(gKl + ka, d + 8192);
    gll16(gKl + ka + RSK, d + 12288);
    gll16(gVh + va, d + 16384);
    gll16(gVh + va + RSV, d + 20480);
    gll16(gVl + va, d + 24576);
    gll16(gVl + va + RSV, d + 28672);
  };

  int slotb[2];
#pragma unroll
  for (int ks = 0; ks < 2; ++ks)
    slotb[ks] = ((ks * 4 + (lane >> 4)) ^ (lane & 7)) << 4;
  const int frow = (lane & 15) * 128;
  const int prow_base = 65536 + (wv * 32 + (lane & 15)) * 128;

  f32x4 oa[2][4];
  float mrow[2][4], lrow[2][4], alpha[2][4];
#pragma unroll
  for (int mf = 0; mf < 2; ++mf)
#pragma unroll
    for (int q = 0; q < 4; ++q) {
      oa[mf][q] = 0.0f;
      mrow[mf][q] = -INFINITY;
      lrow[mf][q] = 0.0f;
    }

  stage(smem, 0);
  int cur = 0;
  for (int jt = 0; jt < NL / 64; ++jt) {
    __syncthreads();
    if (jt + 1 < NL / 64) stage(smem + (cur ^ 1) * 32768, jt + 1);
    const char* sb = smem + cur * 32768;

    // S = Q K^T (scale folded into Q)
    f32x4 s[2][4];
#pragma unroll
    for (int mf = 0; mf < 2; ++mf)
#pragma unroll
      for (int nf = 0; nf < 4; ++nf) s[mf][nf] = 0.0f;
#pragma unroll
    for (int ks = 0; ks < 2; ++ks)
#pragma unroll
      for (int nf = 0; nf < 4; ++nf) {
        int rb = nf * 2048 + frow + slotb[ks];
        bf16x8 kh = *(const bf16x8*)(sb + rb);
        bf16x8 kl = *(const bf16x8*)(sb + 8192 + rb);
#pragma unroll
        for (int mf = 0; mf < 2; ++mf) {
          s[mf][nf] = MFMA16(qh[mf][ks], kh, s[mf][nf], 0, 0, 0);
          s[mf][nf] = MFMA16(qh[mf][ks], kl, s[mf][nf], 0, 0, 0);
          s[mf][nf] = MFMA16(ql[mf][ks], kh, s[mf][nf], 0, 0, 0);
        }
      }

    // online softmax: rows (lane>>4)*4+rg are lane-local; cols via 16-lane shfl
#pragma unroll
    for (int mf = 0; mf < 2; ++mf)
#pragma unroll
      for (int rg = 0; rg < 4; ++rg) {
        float mx = fmaxf(fmaxf(s[mf][0][rg], s[mf][1][rg]),
                         fmaxf(s[mf][2][rg], s[mf][3][rg]));
        mx = fmaxf(mx, __shfl_xor(mx, 1));
        mx = fmaxf(mx, __shfl_xor(mx, 2));
        mx = fmaxf(mx, __shfl_xor(mx, 4));
        mx = fmaxf(mx, __shfl_xor(mx, 8));
        float mo = mrow[mf][rg];
        float mn = fmaxf(mo, mx);
        float al = __expf(mo - mn);
        mrow[mf][rg] = mn;
        alpha[mf][rg] = al;
        float sum = 0.0f;
        int ip = wv * 32 + 16 * mf + (lane >> 4) * 4 + rg;
        int rowb = 65536 + ip * 128;
        int ip7 = ip & 7;
#pragma unroll
        for (int nf = 0; nf < 4; ++nf) {
          float pv = __expf(s[mf][nf][rg] - mn);
          sum += pv;
          int j = 16 * nf + (lane & 15);
          int addr = rowb + ((((j >> 3) ^ ip7) << 4) | ((j & 7) * 2));
          *(u16*)(smem + addr) = bf16_rne(pv);
        }
        sum += __shfl_xor(sum, 1);
        sum += __shfl_xor(sum, 2);
        sum += __shfl_xor(sum, 4);
        sum += __shfl_xor(sum, 8);
        lrow[mf][rg] = al * lrow[mf][rg] + sum;
      }

    // rescale O (rows lane-local, matches mf/rg)
#pragma unroll
    for (int mf = 0; mf < 2; ++mf)
#pragma unroll
      for (int nf = 0; nf < 4; ++nf)
#pragma unroll
        for (int rg = 0; rg < 4; ++rg) oa[mf][nf][rg] *= alpha[mf][rg];

    // O += P * V  (A = P from LDS, B = V natural; D cols = d)
#pragma unroll
    for (int ks = 0; ks < 2; ++ks) {
      bf16x8 pf[2];
#pragma unroll
      for (int mf = 0; mf < 2; ++mf)
        pf[mf] = *(const bf16x8*)(smem + prow_base + mf * 2048 + slotb[ks]);
#pragma unroll
      for (int nf = 0; nf < 4; ++nf) {
        int rv = nf * 2048 + frow + slotb[ks];
        bf16x8 vh = *(const bf16x8*)(sb + 16384 + rv);
        bf16x8 vl = *(const bf16x8*)(sb + 24576 + rv);
#pragma unroll
        for (int mf = 0; mf < 2; ++mf) {
          oa[mf][nf] = MFMA16(pf[mf], vh, oa[mf][nf], 0, 0, 0);
          oa[mf][nf] = MFMA16(pf[mf], vl, oa[mf][nf], 0, 0, 0);
        }
      }
    }
    cur ^= 1;
  }

  // epilogue: O/l -> bf16 hi/lo transposed [b][l][o]
#pragma unroll
  for (int mf = 0; mf < 2; ++mf) {
    float linv[4];
#pragma unroll
    for (int rg = 0; rg < 4; ++rg) linv[rg] = 1.0f / lrow[mf][rg];
#pragma unroll
    for (int rg = 0; rg < 4; ++rg) {
      int i = iw + 16 * mf + (lane >> 4) * 4 + rg;
      size_t orow = ((size_t)b * NL + i) * ND + h * NDH + (lane & 15);
#pragma unroll
      for (int nf = 0; nf < 4; ++nf) {
        float v = oa[mf][nf][rg] * linv[rg];
        u16 hh = bf16_rne(v);
        Oh[orow + 16 * nf] = hh;
        Ol[orow + 16 * nf] = bf16_rne(v - bf16_to_f(hh));
      }
    }
  }
}

// ---------------------------------------------------------------------------
extern "C" void kernel_launch(void* const* d_in, const int* in_sizes, int n_in,
                              void* d_out, int out_size, void* d_ws, size_t ws_size,
                              hipStream_t stream) {
  const float* x = (const float*)d_in[0];
  const float* wq = (const float*)d_in[1];
  const float* wk = (const float*)d_in[2];
  const float* wv = (const float*)d_in[3];
  const float* wo = (const float*)d_in[4];
  const float* bo = (const float*)d_in[5];
  float* out = (float*)d_out;

  const size_t EL = (size_t)NB * ND * NL;  // 8Mi
  char* p = (char*)d_ws;
  u16* Xt_hi = (u16*)p; p += EL * 2;
  u16* Xt_lo = (u16*)p; p += EL * 2;
  u16* Qt_hi = (u16*)p; p += EL * 2;
  u16* Qt_lo = (u16*)p; p += EL * 2;
  u16* Kt_hi = (u16*)p; p += EL * 2;
  u16* Kt_lo = (u16*)p; p += EL * 2;
  u16* Vn_hi = (u16*)p; p += EL * 2;
  u16* Vn_lo = (u16*)p; p += EL * 2;
  const size_t WE = (size_t)ND * ND;
  u16 *Wh[4], *Wl[4];
  for (int i = 0; i < 4; ++i) {
    Wh[i] = (u16*)p; p += WE * 2;
    Wl[i] = (u16*)p; p += WE * 2;
  }
  u16* Ot_hi = Xt_hi;  // Xt dead after V projection -> reuse for O
  u16* Ot_lo = Xt_lo;

  dim3 tpb(256);
  prep_x<<<dim3(NL / 64, ND / 64, NB), tpb, 0, stream>>>(x, Xt_hi, Xt_lo);
  prep_w<<<dim3(WE / 1024), tpb, 0, stream>>>(wq, Wh[0], Wl[0]);
  prep_w<<<dim3(WE / 1024), tpb, 0, stream>>>(wk, Wh[1], Wl[1]);
  prep_w<<<dim3(WE / 1024), tpb, 0, stream>>>(wv, Wh[2], Wl[2]);
  prep_w<<<dim3(WE / 1024), tpb, 0, stream>>>(wo, Wh[3], Wl[3]);

  dim3 gg(NL / 128, ND / 128, NB);
  gemm_split<1><<<gg, tpb, 0, stream>>>(Wh[0], Wl[0], Xt_hi, Xt_lo, nullptr,
                                        nullptr, Qt_hi, Qt_lo, 0.125f);
  gemm_split<1><<<gg, tpb, 0, stream>>>(Wh[1], Wl[1], Xt_hi, Xt_lo, nullptr,
                                        nullptr, Kt_hi, Kt_lo, 1.0f);
  gemm_split<2><<<gg, tpb, 0, stream>>>(Wh[2], Wl[2], Xt_hi, Xt_lo, nullptr,
                                        nullptr, Vn_hi, Vn_lo, 1.0f);

  attn_mfma<<<dim3(NL / 128, NH, NB), tpb, 0, stream>>>(
      Qt_hi, Qt_lo, Kt_hi, Kt_lo, Vn_hi, Vn_lo, Ot_hi, Ot_lo);

  gemm_split<0><<<gg, tpb, 0, stream>>>(Wh[3], Wl[3], Ot_hi, Ot_lo, out, bo,
                                        nullptr, nullptr, 1.0f);
}

// Round 3
// 502.190 us; speedup vs baseline: 4.3229x; 1.2892x over previous
//
#include <hip/hip_runtime.h>
#include <math.h>

#define NB 4
#define ND 1024
#define NL 2048
#define NH 16
#define NDH 64

typedef float f4 __attribute__((ext_vector_type(4)));
typedef float f32x4 __attribute__((ext_vector_type(4)));
typedef short bf16x8 __attribute__((ext_vector_type(8)));
typedef unsigned short u16;
typedef u16 u16x4 __attribute__((ext_vector_type(4)));
typedef unsigned long long u64;

#define MFMA16 __builtin_amdgcn_mfma_f32_16x16x32_bf16

__device__ __forceinline__ u16 bf16_rne(float f) {
  unsigned u = __float_as_uint(f);
  u += 0x7fffu + ((u >> 16) & 1u);
  return (u16)(u >> 16);
}
__device__ __forceinline__ float bf16_to_f(u16 h) {
  return __uint_as_float(((unsigned)h) << 16);
}
__device__ __forceinline__ unsigned cvt_pk_bf16(float a, float b) {
  unsigned r;
  asm("v_cvt_pk_bf16_f32 %0, %1, %2" : "=v"(r) : "v"(a), "v"(b));
  return r;
}
__device__ __forceinline__ void gll16(const void* g, void* l) {
  __builtin_amdgcn_global_load_lds(
      (const __attribute__((address_space(1))) void*)g,
      (__attribute__((address_space(3))) void*)l, 16, 0, 0);
}

// ---------------------------------------------------------------------------
// Prepass: X [b][d][l] fp32 -> Xt hi/lo bf16 [b][l][d] (transpose via LDS)
// ---------------------------------------------------------------------------
__global__ __launch_bounds__(256) void prep_x(const float* __restrict__ X,
                                              u16* __restrict__ Xhi,
                                              u16* __restrict__ Xlo) {
  __shared__ float t[64][65];
  const int tid = threadIdx.x;
  const int l0 = blockIdx.x * 64, d0 = blockIdx.y * 64, b = blockIdx.z;
  const float* Xb = X + ((size_t)b * ND + d0) * NL + l0;
#pragma unroll
  for (int r = 0; r < 16; ++r) {
    int idx = tid + r * 256;
    int d = idx >> 6, l = idx & 63;
    t[d][l] = Xb[(size_t)d * NL + l];
  }
  __syncthreads();
#pragma unroll
  for (int r = 0; r < 16; ++r) {
    int idx = tid + r * 256;
    int li = idx >> 6, dd = idx & 63;
    float v = t[dd][li];
    u16 hh = bf16_rne(v);
    size_t o = ((size_t)b * NL + l0 + li) * ND + d0 + dd;
    Xhi[o] = hh;
    Xlo[o] = bf16_rne(v - bf16_to_f(hh));
  }
}

// ---------------------------------------------------------------------------
// Prepass: W [o][d] fp32 -> hi/lo bf16 (no transpose), 4 elems/thread
// ---------------------------------------------------------------------------
__global__ __launch_bounds__(256) void prep_w(const float* __restrict__ W,
                                              u16* __restrict__ Whi,
                                              u16* __restrict__ Wlo) {
  int i = blockIdx.x * 256 + threadIdx.x;  // grid sized exactly
  f4 v = ((const f4*)W)[i];
  u16x4 h, l;
#pragma unroll
  for (int k = 0; k < 4; ++k) {
    h[k] = bf16_rne(v[k]);
    l[k] = bf16_rne(v[k] - bf16_to_f(h[k]));
  }
  ((u16x4*)Whi)[i] = h;
  ((u16x4*)Wlo)[i] = l;
}

// ---------------------------------------------------------------------------
// Split-bf16 MFMA GEMM: C[b,o,l] = sum_d W[o,d] * X[b,l,d]   (X given l-major)
// 128x128 tile, BK=32, double-buffered LDS, global_load_lds(16B) staging.
// MODE 0: fp32 + bias out [b][o][l]
// MODE 1: bf16 hi/lo transposed out [b][l][o], with scale
// MODE 2: bf16 hi (and lo if non-null) natural out [b][o][l]
// ---------------------------------------------------------------------------
template <int MODE>
__global__ __launch_bounds__(256) void gemm_split(
    const u16* __restrict__ Ahi, const u16* __restrict__ Alo,
    const u16* __restrict__ Bhi, const u16* __restrict__ Blo,
    float* __restrict__ Cf, const float* __restrict__ bias,
    u16* __restrict__ Chi, u16* __restrict__ Clo, float scale) {
  __shared__ char smem[65536];
  const int tid = threadIdx.x;
  const int lane = tid & 63, wv = tid >> 6;
  const int l0 = blockIdx.x * 128, o0 = blockIdx.y * 128, b = blockIdx.z;
  const int wo = (wv >> 1) * 64, wl = (wv & 1) * 64;

  // staging source map (inverse of phys layout); issue q adds 64 rows
  const int pr = tid >> 3;
  const int e = (tid & 7) ^ (pr & 7);
  const int r_src = pr * 2 + (e >> 2);
  const int s_src = e & 3;
  const char* gAh = (const char*)(Ahi + (size_t)(o0 + r_src) * ND) + s_src * 16;
  const char* gAl = (const char*)(Alo + (size_t)(o0 + r_src) * ND) + s_src * 16;
  const char* gBh = (const char*)(Bhi + ((size_t)b * NL + l0 + r_src) * ND) + s_src * 16;
  const char* gBl = (const char*)(Blo + ((size_t)b * NL + l0 + r_src) * ND) + s_src * 16;
  const int QROW = 64 * ND * 2;

  // fragment read offsets (per-lane constant swizzle)
  const int fswz = ((((lane & 1) << 2) | (lane >> 4)) ^ ((lane >> 1) & 7)) << 4;
  int offA[4], offB[4];
#pragma unroll
  for (int f = 0; f < 4; ++f) {
    offA[f] = ((wo + 16 * f + (lane & 15)) >> 1) * 128 + fswz;
    offB[f] = ((wl + 16 * f + (lane & 15)) >> 1) * 128 + fswz;
  }

  f32x4 acc[4][4];
#pragma unroll
  for (int mf = 0; mf < 4; ++mf)
#pragma unroll
    for (int nf = 0; nf < 4; ++nf) acc[mf][nf] = 0.0f;

  auto stage = [&](char* bb, int kbyte) {
    char* d = bb + wv * 1024;
    gll16(gAh + kbyte, d);
    gll16(gAh + kbyte + QROW, d + 4096);
    gll16(gAl + kbyte, d + 8192);
    gll16(gAl + kbyte + QROW, d + 12288);
    gll16(gBh + kbyte, d + 16384);
    gll16(gBh + kbyte + QROW, d + 20480);
    gll16(gBl + kbyte, d + 24576);
    gll16(gBl + kbyte + QROW, d + 28672);
  };

  stage(smem, 0);
  int cur = 0;
  for (int ks = 0; ks < ND / 32; ++ks) {
    __syncthreads();
    if (ks + 1 < ND / 32) stage(smem + (cur ^ 1) * 32768, (ks + 1) * 64);
    const char* sb = smem + cur * 32768;
    bf16x8 ah[4], al[4], bh[4], bl[4];
#pragma unroll
    for (int f = 0; f < 4; ++f) {
      ah[f] = *(const bf16x8*)(sb + offA[f]);
      al[f] = *(const bf16x8*)(sb + 8192 + offA[f]);
      bh[f] = *(const bf16x8*)(sb + 16384 + offB[f]);
      bl[f] = *(const bf16x8*)(sb + 24576 + offB[f]);
    }
    __builtin_amdgcn_s_setprio(1);
#pragma unroll
    for (int mf = 0; mf < 4; ++mf)
#pragma unroll
      for (int nf = 0; nf < 4; ++nf) {
        acc[mf][nf] = MFMA16(ah[mf], bh[nf], acc[mf][nf], 0, 0, 0);
        acc[mf][nf] = MFMA16(ah[mf], bl[nf], acc[mf][nf], 0, 0, 0);
        acc[mf][nf] = MFMA16(al[mf], bh[nf], acc[mf][nf], 0, 0, 0);
      }
    __builtin_amdgcn_s_setprio(0);
    cur ^= 1;
  }

  const int col = lane & 15, row4 = (lane >> 4) * 4;
  if constexpr (MODE == 0) {
    const size_t cb = (size_t)b * ND * NL;
#pragma unroll
    for (int mf = 0; mf < 4; ++mf)
#pragma unroll
      for (int rg = 0; rg < 4; ++rg) {
        int o = o0 + wo + 16 * mf + row4 + rg;
        float bv = bias[o];
        float* crow = Cf + cb + (size_t)o * NL + l0 + wl + col;
#pragma unroll
        for (int nf = 0; nf < 4; ++nf) crow[16 * nf] = acc[mf][nf][rg] + bv;
      }
  } else if constexpr (MODE == 1) {
#pragma unroll
    for (int nf = 0; nf < 4; ++nf) {
      size_t lrow = ((size_t)b * NL + l0 + wl + 16 * nf + col) * ND + o0 + wo;
#pragma unroll
      for (int mf = 0; mf < 4; ++mf) {
        u16x4 h, l;
#pragma unroll
        for (int rg = 0; rg < 4; ++rg) {
          float v = acc[mf][nf][rg] * scale;
          h[rg] = bf16_rne(v);
          l[rg] = bf16_rne(v - bf16_to_f(h[rg]));
        }
        *(u16x4*)(Chi + lrow + 16 * mf + row4) = h;
        *(u16x4*)(Clo + lrow + 16 * mf + row4) = l;
      }
    }
  } else {
    const size_t cb = (size_t)b * ND * NL;
#pragma unroll
    for (int mf = 0; mf < 4; ++mf)
#pragma unroll
      for (int rg = 0; rg < 4; ++rg) {
        int o = o0 + wo + 16 * mf + row4 + rg;
        u16* hrow = Chi + cb + (size_t)o * NL + l0 + wl + col;
#pragma unroll
        for (int nf = 0; nf < 4; ++nf) {
          float v = acc[mf][nf][rg];
          hrow[16 * nf] = bf16_rne(v);
        }
        if (Clo) {
          u16* lrow2 = Clo + cb + (size_t)o * NL + l0 + wl + col;
#pragma unroll
          for (int nf = 0; nf < 4; ++nf) {
            float v = acc[mf][nf][rg];
            lrow2[16 * nf] = bf16_rne(v - bf16_to_f(bf16_rne(v)));
          }
        }
      }
  }
}

// ---------------------------------------------------------------------------
// Flash attention, swapped-operand split-bf16 MFMA.
// Block = 4 waves x 32 query rows = 128 i. Q pre-scaled by log2e/8 (exp2 units).
// S^T = mfma(A=K, B=Q): lane holds 16 j-values for ONE query i=16mf+(lane&15)
//   -> softmax reduce = in-lane tree + shfl_xor(16,32); P packed via
//   v_cvt_pk_bf16_f32 -> ds_write_b64 (XOR-swizzled rows).
// O^T = mfma(A=V natural, B=P^T): D[d][i], per-lane scalar alpha rescale.
// V_lo dropped from PV (error budget allows). K hi/lo kept (3-MFMA split).
// LDS: 2 x 24KB K/V dbuf + 16KB P = 64KB -> 2 blocks/CU.
// ---------------------------------------------------------------------------
__global__ __launch_bounds__(256) void attn_mfma(
    const u16* __restrict__ Qh, const u16* __restrict__ Ql,
    const u16* __restrict__ Kh, const u16* __restrict__ Kl,
    const u16* __restrict__ Vh,
    u16* __restrict__ Oh, u16* __restrict__ Ol) {
  __shared__ char smem[65536];
  const int tid = threadIdx.x, lane = tid & 63, wv = tid >> 6;
  const int il = lane & 15, g = lane >> 4, x7 = il & 7;
  const int i0 = blockIdx.x * 128, h = blockIdx.y, b = blockIdx.z;
  const int iw = i0 + wv * 32;

  // Q fragments in registers: Q[i=16mf+il][d = 32ks + 8g + r]
  bf16x8 qh[2][2], ql[2][2];
  {
#pragma unroll
    for (int mf = 0; mf < 2; ++mf) {
      size_t rowq = ((size_t)b * NL + iw + 16 * mf + il) * ND + h * NDH + g * 8;
#pragma unroll
      for (int ks = 0; ks < 2; ++ks) {
        qh[mf][ks] = *(const bf16x8*)(Qh + rowq + ks * 32);
        ql[mf][ks] = *(const bf16x8*)(Ql + rowq + ks * 32);
      }
    }
  }

  // staging: tiles 64 rows x 128B, slot XOR (r&7)
  const int r0 = tid >> 3;
  const int swz0 = ((tid & 7) ^ (r0 & 7)) << 4;
  const char* gKh = (const char*)(Kh + ((size_t)b * NL + r0) * ND + h * NDH) + swz0;
  const char* gKl = (const char*)(Kl + ((size_t)b * NL + r0) * ND + h * NDH) + swz0;
  const char* gVh = (const char*)(Vh + ((size_t)b * ND + h * NDH + r0) * NL) + swz0;
  const int RSK = 32 * ND * 2, RSV = 32 * NL * 2;
  const int BUF = 24576, PBASE = 49152;

  auto stage = [&](char* bb, int jt) {
    char* d = bb + wv * 1024;
    int ka = jt * (64 * ND * 2);
    int va = jt * 128;
    gll16(gKh + ka, d);
    gll16(gKh + ka + RSK, d + 4096);
    gll16(gKl + ka, d + 8192);
    gll16(gKl + ka + RSK, d + 12288);
    gll16(gVh + va, d + 16384);
    gll16(gVh + va + RSV, d + 20480);
  };

  int slotb[2];
#pragma unroll
  for (int ks = 0; ks < 2; ++ks) slotb[ks] = (((ks << 2) + g) ^ x7) << 4;
  const int frow = il * 128;
  int prow[2];
#pragma unroll
  for (int mf = 0; mf < 2; ++mf)
    prow[mf] = PBASE + (wv * 32 + mf * 16 + il) * 128;

  f32x4 ot[4][2];
  float mrow[2], lrow[2];
#pragma unroll
  for (int df = 0; df < 4; ++df)
#pragma unroll
    for (int mf = 0; mf < 2; ++mf) ot[df][mf] = 0.0f;
  mrow[0] = mrow[1] = -INFINITY;
  lrow[0] = lrow[1] = 0.0f;

  stage(smem, 0);
  int cur = 0;
  for (int jt = 0; jt < NL / 64; ++jt) {
    __syncthreads();
    if (jt + 1 < NL / 64) stage(smem + (cur ^ 1) * BUF, jt + 1);
    const char* sb = smem + cur * BUF;

    // S^T = K · Q^T  (3-MFMA split; scale folded into Q)
    f32x4 st[4][2];
#pragma unroll
    for (int jf = 0; jf < 4; ++jf)
#pragma unroll
      for (int mf = 0; mf < 2; ++mf) st[jf][mf] = 0.0f;
#pragma unroll
    for (int ks = 0; ks < 2; ++ks) {
#pragma unroll
      for (int jf = 0; jf < 4; ++jf) {
        int rb = jf * 2048 + frow + slotb[ks];
        bf16x8 kh = *(const bf16x8*)(sb + rb);
        bf16x8 kl = *(const bf16x8*)(sb + 8192 + rb);
        __builtin_amdgcn_s_setprio(1);
#pragma unroll
        for (int mf = 0; mf < 2; ++mf) {
          st[jf][mf] = MFMA16(kh, qh[mf][ks], st[jf][mf], 0, 0, 0);
          st[jf][mf] = MFMA16(kl, qh[mf][ks], st[jf][mf], 0, 0, 0);
          st[jf][mf] = MFMA16(kh, ql[mf][ks], st[jf][mf], 0, 0, 0);
        }
        __builtin_amdgcn_s_setprio(0);
      }
    }

    // online softmax (exp2 units): per mf, lane owns query i = 16mf+il
    float alpha[2];
#pragma unroll
    for (int mf = 0; mf < 2; ++mf) {
      float mx = st[0][mf][0];
#pragma unroll
      for (int jf = 0; jf < 4; ++jf) {
        float a = fmaxf(st[jf][mf][0], st[jf][mf][1]);
        float c = fmaxf(st[jf][mf][2], st[jf][mf][3]);
        mx = fmaxf(mx, fmaxf(a, c));
      }
      mx = fmaxf(mx, __shfl_xor(mx, 16));
      mx = fmaxf(mx, __shfl_xor(mx, 32));
      float mo = mrow[mf];
      float mn = fmaxf(mo, mx);
      float al = __builtin_amdgcn_exp2f(mo - mn);
      mrow[mf] = mn;
      alpha[mf] = al;
      float sum = 0.0f;
#pragma unroll
      for (int jf = 0; jf < 4; ++jf) {
        float p0 = __builtin_amdgcn_exp2f(st[jf][mf][0] - mn);
        float p1 = __builtin_amdgcn_exp2f(st[jf][mf][1] - mn);
        float p2 = __builtin_amdgcn_exp2f(st[jf][mf][2] - mn);
        float p3 = __builtin_amdgcn_exp2f(st[jf][mf][3] - mn);
        sum += (p0 + p1) + (p2 + p3);
        unsigned w0 = cvt_pk_bf16(p0, p1);
        unsigned w1 = cvt_pk_bf16(p2, p3);
        int addr = prow[mf] + (((2 * jf + (g >> 1)) ^ x7) << 4) + ((g & 1) << 3);
        *(u64*)(smem + addr) = (u64)w0 | ((u64)w1 << 32);
      }
      sum += __shfl_xor(sum, 16);
      sum += __shfl_xor(sum, 32);
      lrow[mf] = al * lrow[mf] + sum;
    }

    // rescale O^T (alpha is per-lane scalar per mf)
#pragma unroll
    for (int df = 0; df < 4; ++df)
#pragma unroll
      for (int mf = 0; mf < 2; ++mf)
#pragma unroll
        for (int rg = 0; rg < 4; ++rg) ot[df][mf][rg] *= alpha[mf];

    // O^T += V · P^T
#pragma unroll
    for (int ks = 0; ks < 2; ++ks) {
      bf16x8 pf[2];
#pragma unroll
      for (int mf = 0; mf < 2; ++mf)
        pf[mf] = *(const bf16x8*)(smem + prow[mf] + ((((ks << 2) + g) ^ x7) << 4));
#pragma unroll
      for (int df = 0; df < 4; ++df) {
        bf16x8 vh = *(const bf16x8*)(sb + 16384 + df * 2048 + frow + slotb[ks]);
        __builtin_amdgcn_s_setprio(1);
        ot[df][0] = MFMA16(vh, pf[0], ot[df][0], 0, 0, 0);
        ot[df][1] = MFMA16(vh, pf[1], ot[df][1], 0, 0, 0);
        __builtin_amdgcn_s_setprio(0);
      }
    }
    cur ^= 1;
  }

  // epilogue: O^T[d][i] -> bf16 hi/lo transposed [b][l=i][o=h*64+d]
#pragma unroll
  for (int mf = 0; mf < 2; ++mf) {
    float linv = 1.0f / lrow[mf];
    size_t orow = ((size_t)b * NL + iw + 16 * mf + il) * ND + h * NDH;
#pragma unroll
    for (int df = 0; df < 4; ++df) {
      u16x4 hh, ll;
#pragma unroll
      for (int rg = 0; rg < 4; ++rg) {
        float v = ot[df][mf][rg] * linv;
        hh[rg] = bf16_rne(v);
        ll[rg] = bf16_rne(v - bf16_to_f(hh[rg]));
      }
      *(u16x4*)(Oh + orow + df * 16 + g * 4) = hh;
      *(u16x4*)(Ol + orow + df * 16 + g * 4) = ll;
    }
  }
}

// ---------------------------------------------------------------------------
extern "C" void kernel_launch(void* const* d_in, const int* in_sizes, int n_in,
                              void* d_out, int out_size, void* d_ws, size_t ws_size,
                              hipStream_t stream) {
  const float* x = (const float*)d_in[0];
  const float* wq = (const float*)d_in[1];
  const float* wk = (const float*)d_in[2];
  const float* wv = (const float*)d_in[3];
  const float* wo = (const float*)d_in[4];
  const float* bo = (const float*)d_in[5];
  float* out = (float*)d_out;

  const size_t EL = (size_t)NB * ND * NL;  // 8Mi
  char* p = (char*)d_ws;
  u16* Xt_hi = (u16*)p; p += EL * 2;
  u16* Xt_lo = (u16*)p; p += EL * 2;
  u16* Qt_hi = (u16*)p; p += EL * 2;
  u16* Qt_lo = (u16*)p; p += EL * 2;
  u16* Kt_hi = (u16*)p; p += EL * 2;
  u16* Kt_lo = (u16*)p; p += EL * 2;
  u16* Vn_hi = (u16*)p; p += EL * 2;
  u16* Vn_lo = (u16*)p; p += EL * 2;  // unused (V_lo dropped)
  const size_t WE = (size_t)ND * ND;
  u16 *Wh[4], *Wl[4];
  for (int i = 0; i < 4; ++i) {
    Wh[i] = (u16*)p; p += WE * 2;
    Wl[i] = (u16*)p; p += WE * 2;
  }
  u16* Ot_hi = Xt_hi;  // Xt dead after V projection -> reuse for O
  u16* Ot_lo = Xt_lo;

  dim3 tpb(256);
  prep_x<<<dim3(NL / 64, ND / 64, NB), tpb, 0, stream>>>(x, Xt_hi, Xt_lo);
  prep_w<<<dim3(WE / 1024), tpb, 0, stream>>>(wq, Wh[0], Wl[0]);
  prep_w<<<dim3(WE / 1024), tpb, 0, stream>>>(wk, Wh[1], Wl[1]);
  prep_w<<<dim3(WE / 1024), tpb, 0, stream>>>(wv, Wh[2], Wl[2]);
  prep_w<<<dim3(WE / 1024), tpb, 0, stream>>>(wo, Wh[3], Wl[3]);

  dim3 gg(NL / 128, ND / 128, NB);
  // Q scale = log2(e)/8 : softmax runs in exp2 units
  gemm_split<1><<<gg, tpb, 0, stream>>>(Wh[0], Wl[0], Xt_hi, Xt_lo, nullptr,
                                        nullptr, Qt_hi, Qt_lo,
                                        0.125f * 1.44269504088896f);
  gemm_split<1><<<gg, tpb, 0, stream>>>(Wh[1], Wl[1], Xt_hi, Xt_lo, nullptr,
                                        nullptr, Kt_hi, Kt_lo, 1.0f);
  gemm_split<2><<<gg, tpb, 0, stream>>>(Wh[2], Wl[2], Xt_hi, Xt_lo, nullptr,
                                        nullptr, Vn_hi, nullptr, 1.0f);

  attn_mfma<<<dim3(NL / 128, NH, NB), tpb, 0, stream>>>(
      Qt_hi, Qt_lo, Kt_hi, Kt_lo, Vn_hi, Ot_hi, Ot_lo);

  gemm_split<0><<<gg, tpb, 0, stream>>>(Wh[3], Wl[3], Ot_hi, Ot_lo, out, bo,
                                        nullptr, nullptr, 1.0f);
}

// Round 4
// 473.021 us; speedup vs baseline: 4.5894x; 1.0617x over previous
//
#include <hip/hip_runtime.h>
#include <math.h>

#define NB 4
#define ND 1024
#define NL 2048
#define NH 16
#define NDH 64

typedef float f4 __attribute__((ext_vector_type(4)));
typedef float f32x4 __attribute__((ext_vector_type(4)));
typedef short bf16x8 __attribute__((ext_vector_type(8)));
typedef unsigned short u16;
typedef u16 u16x4 __attribute__((ext_vector_type(4)));

#define MFMA16 __builtin_amdgcn_mfma_f32_16x16x32_bf16

__device__ __forceinline__ u16 bf16_rne(float f) {
  unsigned u = __float_as_uint(f);
  u += 0x7fffu + ((u >> 16) & 1u);
  return (u16)(u >> 16);
}
__device__ __forceinline__ float bf16_to_f(u16 h) {
  return __uint_as_float(((unsigned)h) << 16);
}
__device__ __forceinline__ unsigned cvt_pk_bf16(float a, float b) {
  unsigned r;
  asm("v_cvt_pk_bf16_f32 %0, %1, %2" : "=v"(r) : "v"(a), "v"(b));
  return r;
}
__device__ __forceinline__ void gll16(const void* g, void* l) {
  __builtin_amdgcn_global_load_lds(
      (const __attribute__((address_space(1))) void*)g,
      (__attribute__((address_space(3))) void*)l, 16, 0, 0);
}

// ---------------------------------------------------------------------------
// Prepass: X [b][d][l] fp32 -> Xt hi/lo bf16 [b][l][d] (transpose via LDS)
// ---------------------------------------------------------------------------
__global__ __launch_bounds__(256) void prep_x(const float* __restrict__ X,
                                              u16* __restrict__ Xhi,
                                              u16* __restrict__ Xlo) {
  __shared__ float t[64][65];
  const int tid = threadIdx.x;
  const int l0 = blockIdx.x * 64, d0 = blockIdx.y * 64, b = blockIdx.z;
  const float* Xb = X + ((size_t)b * ND + d0) * NL + l0;
#pragma unroll
  for (int r = 0; r < 16; ++r) {
    int idx = tid + r * 256;
    int d = idx >> 6, l = idx & 63;
    t[d][l] = Xb[(size_t)d * NL + l];
  }
  __syncthreads();
#pragma unroll
  for (int r = 0; r < 16; ++r) {
    int idx = tid + r * 256;
    int li = idx >> 6, dd = idx & 63;
    float v = t[dd][li];
    u16 hh = bf16_rne(v);
    size_t o = ((size_t)b * NL + l0 + li) * ND + d0 + dd;
    Xhi[o] = hh;
    Xlo[o] = bf16_rne(v - bf16_to_f(hh));
  }
}

// ---------------------------------------------------------------------------
// Prepass: W [o][d] fp32 -> hi/lo bf16 (no transpose), 4 elems/thread
// ---------------------------------------------------------------------------
__global__ __launch_bounds__(256) void prep_w(const float* __restrict__ W,
                                              u16* __restrict__ Whi,
                                              u16* __restrict__ Wlo) {
  int i = blockIdx.x * 256 + threadIdx.x;  // grid sized exactly
  f4 v = ((const f4*)W)[i];
  u16x4 h, l;
#pragma unroll
  for (int k = 0; k < 4; ++k) {
    h[k] = bf16_rne(v[k]);
    l[k] = bf16_rne(v[k] - bf16_to_f(h[k]));
  }
  ((u16x4*)Whi)[i] = h;
  ((u16x4*)Wlo)[i] = l;
}

// ---------------------------------------------------------------------------
// Split-bf16 MFMA GEMM: C[b,o,l] = sum_d W[o,d] * X[b,l,d]   (X given l-major)
// 128x128 tile, BK=32, double-buffered LDS, global_load_lds(16B) staging.
// MODE 0: fp32 + bias out [b][o][l]
// MODE 1: bf16 hi/lo transposed out [b][l][o], with scale
// MODE 2: bf16 hi (and lo if non-null) natural out [b][o][l]
// ---------------------------------------------------------------------------
template <int MODE>
__global__ __launch_bounds__(256) void gemm_split(
    const u16* __restrict__ Ahi, const u16* __restrict__ Alo,
    const u16* __restrict__ Bhi, const u16* __restrict__ Blo,
    float* __restrict__ Cf, const float* __restrict__ bias,
    u16* __restrict__ Chi, u16* __restrict__ Clo, float scale) {
  __shared__ char smem[65536];
  const int tid = threadIdx.x;
  const int lane = tid & 63, wv = tid >> 6;
  const int l0 = blockIdx.x * 128, o0 = blockIdx.y * 128, b = blockIdx.z;
  const int wo = (wv >> 1) * 64, wl = (wv & 1) * 64;

  // staging source map (inverse of phys layout); issue q adds 64 rows
  const int pr = tid >> 3;
  const int e = (tid & 7) ^ (pr & 7);
  const int r_src = pr * 2 + (e >> 2);
  const int s_src = e & 3;
  const char* gAh = (const char*)(Ahi + (size_t)(o0 + r_src) * ND) + s_src * 16;
  const char* gAl = (const char*)(Alo + (size_t)(o0 + r_src) * ND) + s_src * 16;
  const char* gBh = (const char*)(Bhi + ((size_t)b * NL + l0 + r_src) * ND) + s_src * 16;
  const char* gBl = (const char*)(Blo + ((size_t)b * NL + l0 + r_src) * ND) + s_src * 16;
  const int QROW = 64 * ND * 2;

  // fragment read offsets (per-lane constant swizzle)
  const int fswz = ((((lane & 1) << 2) | (lane >> 4)) ^ ((lane >> 1) & 7)) << 4;
  int offA[4], offB[4];
#pragma unroll
  for (int f = 0; f < 4; ++f) {
    offA[f] = ((wo + 16 * f + (lane & 15)) >> 1) * 128 + fswz;
    offB[f] = ((wl + 16 * f + (lane & 15)) >> 1) * 128 + fswz;
  }

  f32x4 acc[4][4];
#pragma unroll
  for (int mf = 0; mf < 4; ++mf)
#pragma unroll
    for (int nf = 0; nf < 4; ++nf) acc[mf][nf] = 0.0f;

  auto stage = [&](char* bb, int kbyte) {
    char* d = bb + wv * 1024;
    gll16(gAh + kbyte, d);
    gll16(gAh + kbyte + QROW, d + 4096);
    gll16(gAl + kbyte, d + 8192);
    gll16(gAl + kbyte + QROW, d + 12288);
    gll16(gBh + kbyte, d + 16384);
    gll16(gBh + kbyte + QROW, d + 20480);
    gll16(gBl + kbyte, d + 24576);
    gll16(gBl + kbyte + QROW, d + 28672);
  };

  stage(smem, 0);
  int cur = 0;
  for (int ks = 0; ks < ND / 32; ++ks) {
    __syncthreads();
    if (ks + 1 < ND / 32) stage(smem + (cur ^ 1) * 32768, (ks + 1) * 64);
    const char* sb = smem + cur * 32768;
    bf16x8 ah[4], al[4], bh[4], bl[4];
#pragma unroll
    for (int f = 0; f < 4; ++f) {
      ah[f] = *(const bf16x8*)(sb + offA[f]);
      al[f] = *(const bf16x8*)(sb + 8192 + offA[f]);
      bh[f] = *(const bf16x8*)(sb + 16384 + offB[f]);
      bl[f] = *(const bf16x8*)(sb + 24576 + offB[f]);
    }
    __builtin_amdgcn_s_setprio(1);
#pragma unroll
    for (int mf = 0; mf < 4; ++mf)
#pragma unroll
      for (int nf = 0; nf < 4; ++nf) {
        acc[mf][nf] = MFMA16(ah[mf], bh[nf], acc[mf][nf], 0, 0, 0);
        acc[mf][nf] = MFMA16(ah[mf], bl[nf], acc[mf][nf], 0, 0, 0);
        acc[mf][nf] = MFMA16(al[mf], bh[nf], acc[mf][nf], 0, 0, 0);
      }
    __builtin_amdgcn_s_setprio(0);
    cur ^= 1;
  }

  const int col = lane & 15, row4 = (lane >> 4) * 4;
  if constexpr (MODE == 0) {
    const size_t cb = (size_t)b * ND * NL;
#pragma unroll
    for (int mf = 0; mf < 4; ++mf)
#pragma unroll
      for (int rg = 0; rg < 4; ++rg) {
        int o = o0 + wo + 16 * mf + row4 + rg;
        float bv = bias[o];
        float* crow = Cf + cb + (size_t)o * NL + l0 + wl + col;
#pragma unroll
        for (int nf = 0; nf < 4; ++nf) crow[16 * nf] = acc[mf][nf][rg] + bv;
      }
  } else if constexpr (MODE == 1) {
#pragma unroll
    for (int nf = 0; nf < 4; ++nf) {
      size_t lrow = ((size_t)b * NL + l0 + wl + 16 * nf + col) * ND + o0 + wo;
#pragma unroll
      for (int mf = 0; mf < 4; ++mf) {
        u16x4 h, l;
#pragma unroll
        for (int rg = 0; rg < 4; ++rg) {
          float v = acc[mf][nf][rg] * scale;
          h[rg] = bf16_rne(v);
          l[rg] = bf16_rne(v - bf16_to_f(h[rg]));
        }
        *(u16x4*)(Chi + lrow + 16 * mf + row4) = h;
        *(u16x4*)(Clo + lrow + 16 * mf + row4) = l;
      }
    }
  } else {
    const size_t cb = (size_t)b * ND * NL;
#pragma unroll
    for (int mf = 0; mf < 4; ++mf)
#pragma unroll
      for (int rg = 0; rg < 4; ++rg) {
        int o = o0 + wo + 16 * mf + row4 + rg;
        u16* hrow = Chi + cb + (size_t)o * NL + l0 + wl + col;
#pragma unroll
        for (int nf = 0; nf < 4; ++nf) {
          float v = acc[mf][nf][rg];
          hrow[16 * nf] = bf16_rne(v);
        }
        if (Clo) {
          u16* lrow2 = Clo + cb + (size_t)o * NL + l0 + wl + col;
#pragma unroll
          for (int nf = 0; nf < 4; ++nf) {
            float v = acc[mf][nf][rg];
            lrow2[16 * nf] = bf16_rne(v - bf16_to_f(bf16_rne(v)));
          }
        }
      }
  }
}

// ---------------------------------------------------------------------------
// Flash attention, swapped-operand split-bf16 MFMA, P fully in registers.
// Block = 4 waves x 32 query rows = 128 i. Q pre-scaled by log2e/8 (exp2 units).
// S^T = mfma(A=K, B=Q): lane (g=lane>>4, il=lane&15) holds
//   P[i=il(+16mf)][j = 16jf + 4g + rg].
// P -> PV B-frag via cvt_pk + permlane32_swap + permlane16_swap:
//   {u0,u2} = pl16swap(pl32swap(pk[2ks][pp], pk[2ks+1][pp])) gives lane g'
//   P[il][32ks+8g'+r] in reg order r=0..7 (derivation verified element-wise).
// defer-max (T13): skip m-update/rescale when __all(pmax <= m + 11.5) (exp2).
// LDS: 2 x 24KB K/V dbuf = 48KB -> 3 blocks/CU.
// ---------------------------------------------------------------------------
__global__ __launch_bounds__(256) void attn_mfma(
    const u16* __restrict__ Qh, const u16* __restrict__ Ql,
    const u16* __restrict__ Kh, const u16* __restrict__ Kl,
    const u16* __restrict__ Vh,
    u16* __restrict__ Oh, u16* __restrict__ Ol) {
  __shared__ char smem[49152];
  const int tid = threadIdx.x, lane = tid & 63, wv = tid >> 6;
  const int il = lane & 15, g = lane >> 4, x7 = il & 7;
  const int i0 = blockIdx.x * 128, h = blockIdx.y, b = blockIdx.z;
  const int iw = i0 + wv * 32;

  // Q fragments in registers: Q[i=16mf+il][d = 32ks + 8g + r]
  bf16x8 qh[2][2], ql[2][2];
  {
#pragma unroll
    for (int mf = 0; mf < 2; ++mf) {
      size_t rowq = ((size_t)b * NL + iw + 16 * mf + il) * ND + h * NDH + g * 8;
#pragma unroll
      for (int ks = 0; ks < 2; ++ks) {
        qh[mf][ks] = *(const bf16x8*)(Qh + rowq + ks * 32);
        ql[mf][ks] = *(const bf16x8*)(Ql + rowq + ks * 32);
      }
    }
  }

  // staging: tiles 64 rows x 128B, slot XOR (r&7)
  const int r0 = tid >> 3;
  const int swz0 = ((tid & 7) ^ (r0 & 7)) << 4;
  const char* gKh = (const char*)(Kh + ((size_t)b * NL + r0) * ND + h * NDH) + swz0;
  const char* gKl = (const char*)(Kl + ((size_t)b * NL + r0) * ND + h * NDH) + swz0;
  const char* gVh = (const char*)(Vh + ((size_t)b * ND + h * NDH + r0) * NL) + swz0;
  const int RSK = 32 * ND * 2, RSV = 32 * NL * 2;
  const int BUF = 24576;

  auto stage = [&](char* bb, int jt) {
    char* d = bb + wv * 1024;
    int ka = jt * (64 * ND * 2);
    int va = jt * 128;
    gll16(gKh + ka, d);
    gll16(gKh + ka + RSK, d + 4096);
    gll16(gKl + ka, d + 8192);
    gll16(gKl + ka + RSK, d + 12288);
    gll16(gVh + va, d + 16384);
    gll16(gVh + va + RSV, d + 20480);
  };

  int slotb[2];
#pragma unroll
  for (int ks = 0; ks < 2; ++ks) slotb[ks] = (((ks << 2) + g) ^ x7) << 4;
  const int frow = il * 128;

  f32x4 ot[4][2];
  float mrow[2], lrow[2];
#pragma unroll
  for (int df = 0; df < 4; ++df)
#pragma unroll
    for (int mf = 0; mf < 2; ++mf) ot[df][mf] = 0.0f;
  mrow[0] = mrow[1] = -INFINITY;
  lrow[0] = lrow[1] = 0.0f;

  stage(smem, 0);
  int cur = 0;
  for (int jt = 0; jt < NL / 64; ++jt) {
    __syncthreads();
    if (jt + 1 < NL / 64) stage(smem + (cur ^ 1) * BUF, jt + 1);
    const char* sb = smem + cur * BUF;

    // S^T = K · Q^T  (3-MFMA split; scale folded into Q)
    f32x4 st[4][2];
#pragma unroll
    for (int jf = 0; jf < 4; ++jf)
#pragma unroll
      for (int mf = 0; mf < 2; ++mf) st[jf][mf] = 0.0f;
#pragma unroll
    for (int ks = 0; ks < 2; ++ks) {
#pragma unroll
      for (int jf = 0; jf < 4; ++jf) {
        int rb = jf * 2048 + frow + slotb[ks];
        bf16x8 kh = *(const bf16x8*)(sb + rb);
        bf16x8 kl = *(const bf16x8*)(sb + 8192 + rb);
        __builtin_amdgcn_s_setprio(1);
#pragma unroll
        for (int mf = 0; mf < 2; ++mf) {
          st[jf][mf] = MFMA16(kh, qh[mf][ks], st[jf][mf], 0, 0, 0);
          st[jf][mf] = MFMA16(kl, qh[mf][ks], st[jf][mf], 0, 0, 0);
          st[jf][mf] = MFMA16(kh, ql[mf][ks], st[jf][mf], 0, 0, 0);
        }
        __builtin_amdgcn_s_setprio(0);
      }
    }

    // per-query tile max (rows lane-local; reduce over g via shfl 16/32)
    float mx2[2];
#pragma unroll
    for (int mf = 0; mf < 2; ++mf) {
      float mx = -INFINITY;
#pragma unroll
      for (int jf = 0; jf < 4; ++jf) {
        float a = fmaxf(st[jf][mf][0], st[jf][mf][1]);
        float c = fmaxf(st[jf][mf][2], st[jf][mf][3]);
        mx = fmaxf(mx, fmaxf(a, c));
      }
      mx = fmaxf(mx, __shfl_xor(mx, 16));
      mx = fmaxf(mx, __shfl_xor(mx, 32));
      mx2[mf] = mx;
    }
    // defer-max: skip rescale when tile max doesn't push m by > 11.5 (exp2 units)
    const int defer =
        __all((mx2[0] <= mrow[0] + 11.5f) && (mx2[1] <= mrow[1] + 11.5f));

    bf16x8 pfrag[2][2];
#pragma unroll
    for (int mf = 0; mf < 2; ++mf) {
      if (!defer) {
        float mn = fmaxf(mrow[mf], mx2[mf]);
        float al = __builtin_amdgcn_exp2f(mrow[mf] - mn);
        mrow[mf] = mn;
        lrow[mf] *= al;
#pragma unroll
        for (int df = 0; df < 4; ++df)
#pragma unroll
          for (int rg = 0; rg < 4; ++rg) ot[df][mf][rg] *= al;
      }
      const float mn = mrow[mf];
      float sum = 0.0f;
      unsigned pk[4][2];
#pragma unroll
      for (int jf = 0; jf < 4; ++jf) {
        float p0 = __builtin_amdgcn_exp2f(st[jf][mf][0] - mn);
        float p1 = __builtin_amdgcn_exp2f(st[jf][mf][1] - mn);
        float p2 = __builtin_amdgcn_exp2f(st[jf][mf][2] - mn);
        float p3 = __builtin_amdgcn_exp2f(st[jf][mf][3] - mn);
        sum += (p0 + p1) + (p2 + p3);
        pk[jf][0] = cvt_pk_bf16(p0, p1);
        pk[jf][1] = cvt_pk_bf16(p2, p3);
      }
      sum += __shfl_xor(sum, 16);
      sum += __shfl_xor(sum, 32);
      lrow[mf] += sum;

      // register redistribution -> PV B-fragments
#pragma unroll
      for (int ks = 0; ks < 2; ++ks) {
        unsigned u0, u1, u2, u3;
        {
          unsigned a = pk[2 * ks][0], bb2 = pk[2 * ks + 1][0];
          asm volatile("v_permlane32_swap_b32 %0, %1" : "+v"(a), "+v"(bb2));
          asm volatile("v_permlane16_swap_b32 %0, %1" : "+v"(a), "+v"(bb2));
          u0 = a; u2 = bb2;
        }
        {
          unsigned a = pk[2 * ks][1], bb2 = pk[2 * ks + 1][1];
          asm volatile("v_permlane32_swap_b32 %0, %1" : "+v"(a), "+v"(bb2));
          asm volatile("v_permlane16_swap_b32 %0, %1" : "+v"(a), "+v"(bb2));
          u1 = a; u3 = bb2;
        }
        union { unsigned w[4]; bf16x8 v; } cv;
        cv.w[0] = u0; cv.w[1] = u1; cv.w[2] = u2; cv.w[3] = u3;
        pfrag[mf][ks] = cv.v;
      }
    }

    // O^T += V · P^T
#pragma unroll
    for (int ks = 0; ks < 2; ++ks) {
#pragma unroll
      for (int df = 0; df < 4; ++df) {
        bf16x8 vh = *(const bf16x8*)(sb + 16384 + df * 2048 + frow + slotb[ks]);
        __builtin_amdgcn_s_setprio(1);
        ot[df][0] = MFMA16(vh, pfrag[0][ks], ot[df][0], 0, 0, 0);
        ot[df][1] = MFMA16(vh, pfrag[1][ks], ot[df][1], 0, 0, 0);
        __builtin_amdgcn_s_setprio(0);
      }
    }
    cur ^= 1;
  }

  // epilogue: O^T[d][i] -> bf16 hi/lo transposed [b][l=i][o=h*64+d]
#pragma unroll
  for (int mf = 0; mf < 2; ++mf) {
    float linv = 1.0f / lrow[mf];
    size_t orow = ((size_t)b * NL + iw + 16 * mf + il) * ND + h * NDH;
#pragma unroll
    for (int df = 0; df < 4; ++df) {
      u16x4 hh, ll;
#pragma unroll
      for (int rg = 0; rg < 4; ++rg) {
        float v = ot[df][mf][rg] * linv;
        hh[rg] = bf16_rne(v);
        ll[rg] = bf16_rne(v - bf16_to_f(hh[rg]));
      }
      *(u16x4*)(Oh + orow + df * 16 + g * 4) = hh;
      *(u16x4*)(Ol + orow + df * 16 + g * 4) = ll;
    }
  }
}

// ---------------------------------------------------------------------------
extern "C" void kernel_launch(void* const* d_in, const int* in_sizes, int n_in,
                              void* d_out, int out_size, void* d_ws, size_t ws_size,
                              hipStream_t stream) {
  const float* x = (const float*)d_in[0];
  const float* wq = (const float*)d_in[1];
  const float* wk = (const float*)d_in[2];
  const float* wv = (const float*)d_in[3];
  const float* wo = (const float*)d_in[4];
  const float* bo = (const float*)d_in[5];
  float* out = (float*)d_out;

  const size_t EL = (size_t)NB * ND * NL;  // 8Mi
  char* p = (char*)d_ws;
  u16* Xt_hi = (u16*)p; p += EL * 2;
  u16* Xt_lo = (u16*)p; p += EL * 2;
  u16* Qt_hi = (u16*)p; p += EL * 2;
  u16* Qt_lo = (u16*)p; p += EL * 2;
  u16* Kt_hi = (u16*)p; p += EL * 2;
  u16* Kt_lo = (u16*)p; p += EL * 2;
  u16* Vn_hi = (u16*)p; p += EL * 2;
  u16* Vn_lo = (u16*)p; p += EL * 2;  // unused (V_lo dropped)
  const size_t WE = (size_t)ND * ND;
  u16 *Wh[4], *Wl[4];
  for (int i = 0; i < 4; ++i) {
    Wh[i] = (u16*)p; p += WE * 2;
    Wl[i] = (u16*)p; p += WE * 2;
  }
  u16* Ot_hi = Xt_hi;  // Xt dead after V projection -> reuse for O
  u16* Ot_lo = Xt_lo;

  dim3 tpb(256);
  prep_x<<<dim3(NL / 64, ND / 64, NB), tpb, 0, stream>>>(x, Xt_hi, Xt_lo);
  prep_w<<<dim3(WE / 1024), tpb, 0, stream>>>(wq, Wh[0], Wl[0]);
  prep_w<<<dim3(WE / 1024), tpb, 0, stream>>>(wk, Wh[1], Wl[1]);
  prep_w<<<dim3(WE / 1024), tpb, 0, stream>>>(wv, Wh[2], Wl[2]);
  prep_w<<<dim3(WE / 1024), tpb, 0, stream>>>(wo, Wh[3], Wl[3]);

  dim3 gg(NL / 128, ND / 128, NB);
  // Q scale = log2(e)/8 : softmax runs in exp2 units
  gemm_split<1><<<gg, tpb, 0, stream>>>(Wh[0], Wl[0], Xt_hi, Xt_lo, nullptr,
                                        nullptr, Qt_hi, Qt_lo,
                                        0.125f * 1.44269504088896f);
  gemm_split<1><<<gg, tpb, 0, stream>>>(Wh[1], Wl[1], Xt_hi, Xt_lo, nullptr,
                                        nullptr, Kt_hi, Kt_lo, 1.0f);
  gemm_split<2><<<gg, tpb, 0, stream>>>(Wh[2], Wl[2], Xt_hi, Xt_lo, nullptr,
                                        nullptr, Vn_hi, nullptr, 1.0f);

  attn_mfma<<<dim3(NL / 128, NH, NB), tpb, 0, stream>>>(
      Qt_hi, Qt_lo, Kt_hi, Kt_lo, Vn_hi, Ot_hi, Ot_lo);

  gemm_split<0><<<gg, tpb, 0, stream>>>(Wh[3], Wl[3], Ot_hi, Ot_lo, out, bo,
                                        nullptr, nullptr, 1.0f);
}

// Round 6
// 436.435 us; speedup vs baseline: 4.9742x; 1.0838x over previous
//
#include <hip/hip_runtime.h>
#include <math.h>

#define NB 4
#define ND 1024
#define NL 2048
#define NH 16
#define NDH 64

typedef float f4 __attribute__((ext_vector_type(4)));
typedef float f32x4 __attribute__((ext_vector_type(4)));
typedef short bf16x8 __attribute__((ext_vector_type(8)));
typedef _Float16 f16x8 __attribute__((ext_vector_type(8)));
typedef unsigned short u16;
typedef u16 u16x4 __attribute__((ext_vector_type(4)));

#define MFMA16 __builtin_amdgcn_mfma_f32_16x16x32_bf16
#define MFMA16F __builtin_amdgcn_mfma_f32_16x16x32_f16

__device__ __forceinline__ u16 bf16_rne(float f) {
  unsigned u = __float_as_uint(f);
  u += 0x7fffu + ((u >> 16) & 1u);
  return (u16)(u >> 16);
}
__device__ __forceinline__ float bf16_to_f(u16 h) {
  return __uint_as_float(((unsigned)h) << 16);
}
__device__ __forceinline__ u16 f16_bits(float f) {
  union { _Float16 h; u16 u; } t;
  t.h = (_Float16)f;
  return t.u;
}
__device__ __forceinline__ float f16_val(u16 b) {
  union { _Float16 h; u16 u; } t;
  t.u = b;
  return (float)t.h;
}
__device__ __forceinline__ unsigned cvt_pk_bf16(float a, float b) {
  unsigned r;
  asm("v_cvt_pk_bf16_f32 %0, %1, %2" : "=v"(r) : "v"(a), "v"(b));
  return r;
}
__device__ __forceinline__ void gll16(const void* g, void* l) {
  __builtin_amdgcn_global_load_lds(
      (const __attribute__((address_space(1))) void*)g,
      (__attribute__((address_space(3))) void*)l, 16, 0, 0);
}

// dtype-dispatched MFMA on raw 16B registers
template <int TERMS>
__device__ __forceinline__ f32x4 mma(bf16x8 a, bf16x8 b, f32x4 c) {
  if constexpr (TERMS == 2) {
    union { bf16x8 s; f16x8 h; } ua, ub;
    ua.s = a; ub.s = b;
    return MFMA16F(ua.h, ub.h, c, 0, 0, 0);
  } else {
    return MFMA16(a, b, c, 0, 0, 0);
  }
}

// ---------------------------------------------------------------------------
// Prepass: X [b][d][l] fp32 -> Xt hi/lo FP16 [b][l][d] (transpose via LDS)
// ---------------------------------------------------------------------------
__global__ __launch_bounds__(256) void prep_x(const float* __restrict__ X,
                                              u16* __restrict__ Xhi,
                                              u16* __restrict__ Xlo) {
  __shared__ float t[64][65];
  const int tid = threadIdx.x;
  const int l0 = blockIdx.x * 64, d0 = blockIdx.y * 64, b = blockIdx.z;
  const float* Xb = X + ((size_t)b * ND + d0) * NL + l0;
#pragma unroll
  for (int r = 0; r < 16; ++r) {
    int idx = tid + r * 256;
    int d = idx >> 6, l = idx & 63;
    t[d][l] = Xb[(size_t)d * NL + l];
  }
  __syncthreads();
#pragma unroll
  for (int r = 0; r < 16; ++r) {
    int idx = tid + r * 256;
    int li = idx >> 6, dd = idx & 63;
    float v = t[dd][li];
    u16 hh = f16_bits(v);
    size_t o = ((size_t)b * NL + l0 + li) * ND + d0 + dd;
    Xhi[o] = hh;
    Xlo[o] = f16_bits(v - f16_val(hh));
  }
}

// ---------------------------------------------------------------------------
// Prepass: W [o][d] fp32 -> hi/lo bf16 (for the bf16 3-term WO GEMM)
// ---------------------------------------------------------------------------
__global__ __launch_bounds__(256) void prep_w_bf(const float* __restrict__ W,
                                                 u16* __restrict__ Whi,
                                                 u16* __restrict__ Wlo) {
  int i = blockIdx.x * 256 + threadIdx.x;
  f4 v = ((const f4*)W)[i];
  u16x4 h, l;
#pragma unroll
  for (int k = 0; k < 4; ++k) {
    h[k] = bf16_rne(v[k]);
    l[k] = bf16_rne(v[k] - bf16_to_f(h[k]));
  }
  ((u16x4*)Whi)[i] = h;
  ((u16x4*)Wlo)[i] = l;
}

// ---------------------------------------------------------------------------
// Prepass: W [o][d] fp32 -> single FP16 (for the 2-term QKV GEMMs)
// ---------------------------------------------------------------------------
__global__ __launch_bounds__(256) void prep_w_f16(const float* __restrict__ W,
                                                  u16* __restrict__ Whi) {
  int i = blockIdx.x * 256 + threadIdx.x;
  f4 v = ((const f4*)W)[i];
  u16x4 h;
#pragma unroll
  for (int k = 0; k < 4; ++k) h[k] = f16_bits(v[k]);
  ((u16x4*)Whi)[i] = h;
}

// ---------------------------------------------------------------------------
// MFMA GEMM: C[b,o,l] = sum_d W[o,d] * X[b,l,d]   (X given l-major)
// 128x128 tile, BK=32, double-buffered LDS, global_load_lds(16B) staging.
// TERMS=3: bf16 A hi/lo + B hi/lo, 3 MFMAs (W*X ~ 2^-16).
// TERMS=2: fp16 A single + B hi/lo, 2 MFMAs (W*X ~ W-ulp 2^-11 only).
// MODE 0: fp32 + bias out [b][o][l]
// MODE 1: bf16 hi/lo transposed out [b][l][o], with scale
// MODE 2: bf16 hi (and lo if non-null) natural out [b][o][l]
// ---------------------------------------------------------------------------
template <int MODE, int TERMS>
__global__ __launch_bounds__(256) void gemm_split(
    const u16* __restrict__ Ahi, const u16* __restrict__ Alo,
    const u16* __restrict__ Bhi, const u16* __restrict__ Blo,
    float* __restrict__ Cf, const float* __restrict__ bias,
    u16* __restrict__ Chi, u16* __restrict__ Clo, float scale) {
  constexpr int BUFSZ = (TERMS == 3) ? 32768 : 24576;
  constexpr int BH_OFF = (TERMS == 3) ? 16384 : 8192;
  constexpr int BL_OFF = (TERMS == 3) ? 24576 : 16384;
  __shared__ char smem[2 * BUFSZ];
  const int tid = threadIdx.x;
  const int lane = tid & 63, wv = tid >> 6;
  const int l0 = blockIdx.x * 128, o0 = blockIdx.y * 128, b = blockIdx.z;
  const int wo = (wv >> 1) * 64, wl = (wv & 1) * 64;

  // staging source map (inverse of phys layout); issue q adds 64 rows
  const int pr = tid >> 3;
  const int e = (tid & 7) ^ (pr & 7);
  const int r_src = pr * 2 + (e >> 2);
  const int s_src = e & 3;
  const char* gAh = (const char*)(Ahi + (size_t)(o0 + r_src) * ND) + s_src * 16;
  const char* gAl = (const char*)(Alo + (size_t)(o0 + r_src) * ND) + s_src * 16;
  const char* gBh = (const char*)(Bhi + ((size_t)b * NL + l0 + r_src) * ND) + s_src * 16;
  const char* gBl = (const char*)(Blo + ((size_t)b * NL + l0 + r_src) * ND) + s_src * 16;
  const int QROW = 64 * ND * 2;

  // fragment read offsets (per-lane constant swizzle)
  const int fswz = ((((lane & 1) << 2) | (lane >> 4)) ^ ((lane >> 1) & 7)) << 4;
  int offA[4], offB[4];
#pragma unroll
  for (int f = 0; f < 4; ++f) {
    offA[f] = ((wo + 16 * f + (lane & 15)) >> 1) * 128 + fswz;
    offB[f] = ((wl + 16 * f + (lane & 15)) >> 1) * 128 + fswz;
  }

  f32x4 acc[4][4];
#pragma unroll
  for (int mf = 0; mf < 4; ++mf)
#pragma unroll
    for (int nf = 0; nf < 4; ++nf) acc[mf][nf] = 0.0f;

  auto stage = [&](char* bb, int kbyte) {
    char* d = bb + wv * 1024;
    gll16(gAh + kbyte, d);
    gll16(gAh + kbyte + QROW, d + 4096);
    if constexpr (TERMS == 3) {
      gll16(gAl + kbyte, d + 8192);
      gll16(gAl + kbyte + QROW, d + 12288);
    }
    gll16(gBh + kbyte, d + BH_OFF);
    gll16(gBh + kbyte + QROW, d + BH_OFF + 4096);
    gll16(gBl + kbyte, d + BL_OFF);
    gll16(gBl + kbyte + QROW, d + BL_OFF + 4096);
  };

  stage(smem, 0);
  int cur = 0;
  for (int ks = 0; ks < ND / 32; ++ks) {
    __syncthreads();
    if (ks + 1 < ND / 32) stage(smem + (cur ^ 1) * BUFSZ, (ks + 1) * 64);
    const char* sb = smem + cur * BUFSZ;
    bf16x8 ah[4], al[4], bh[4], bl[4];
#pragma unroll
    for (int f = 0; f < 4; ++f) {
      ah[f] = *(const bf16x8*)(sb + offA[f]);
      if constexpr (TERMS == 3) al[f] = *(const bf16x8*)(sb + 8192 + offA[f]);
      bh[f] = *(const bf16x8*)(sb + BH_OFF + offB[f]);
      bl[f] = *(const bf16x8*)(sb + BL_OFF + offB[f]);
    }
    __builtin_amdgcn_s_setprio(1);
#pragma unroll
    for (int mf = 0; mf < 4; ++mf)
#pragma unroll
      for (int nf = 0; nf < 4; ++nf) {
        acc[mf][nf] = mma<TERMS>(ah[mf], bh[nf], acc[mf][nf]);
        acc[mf][nf] = mma<TERMS>(ah[mf], bl[nf], acc[mf][nf]);
        if constexpr (TERMS == 3)
          acc[mf][nf] = mma<TERMS>(al[mf], bh[nf], acc[mf][nf]);
      }
    __builtin_amdgcn_s_setprio(0);
    cur ^= 1;
  }

  const int col = lane & 15, row4 = (lane >> 4) * 4;
  if constexpr (MODE == 0) {
    const size_t cb = (size_t)b * ND * NL;
#pragma unroll
    for (int mf = 0; mf < 4; ++mf)
#pragma unroll
      for (int rg = 0; rg < 4; ++rg) {
        int o = o0 + wo + 16 * mf + row4 + rg;
        float bv = bias[o];
        float* crow = Cf + cb + (size_t)o * NL + l0 + wl + col;
#pragma unroll
        for (int nf = 0; nf < 4; ++nf) crow[16 * nf] = acc[mf][nf][rg] + bv;
      }
  } else if constexpr (MODE == 1) {
#pragma unroll
    for (int nf = 0; nf < 4; ++nf) {
      size_t lrow = ((size_t)b * NL + l0 + wl + 16 * nf + col) * ND + o0 + wo;
#pragma unroll
      for (int mf = 0; mf < 4; ++mf) {
        u16x4 h, l;
#pragma unroll
        for (int rg = 0; rg < 4; ++rg) {
          float v = acc[mf][nf][rg] * scale;
          h[rg] = bf16_rne(v);
          l[rg] = bf16_rne(v - bf16_to_f(h[rg]));
        }
        *(u16x4*)(Chi + lrow + 16 * mf + row4) = h;
        *(u16x4*)(Clo + lrow + 16 * mf + row4) = l;
      }
    }
  } else {
    const size_t cb = (size_t)b * ND * NL;
#pragma unroll
    for (int mf = 0; mf < 4; ++mf)
#pragma unroll
      for (int rg = 0; rg < 4; ++rg) {
        int o = o0 + wo + 16 * mf + row4 + rg;
        u16* hrow = Chi + cb + (size_t)o * NL + l0 + wl + col;
#pragma unroll
        for (int nf = 0; nf < 4; ++nf) {
          float v = acc[mf][nf][rg];
          hrow[16 * nf] = bf16_rne(v);
        }
        if (Clo) {
          u16* lrow2 = Clo + cb + (size_t)o * NL + l0 + wl + col;
#pragma unroll
          for (int nf = 0; nf < 4; ++nf) {
            float v = acc[mf][nf][rg];
            lrow2[16 * nf] = bf16_rne(v - bf16_to_f(bf16_rne(v)));
          }
        }
      }
  }
}

// ---------------------------------------------------------------------------
// Flash attention (EXACT round-4 kernel, known good incl. graph replay).
// Swapped-operand split-bf16 MFMA, P fully in registers.
// Block = 4 waves x 32 query rows = 128 i. Q pre-scaled by log2e/8 (exp2 units).
// S^T = mfma(A=K, B=Q): lane (g=lane>>4, il=lane&15) holds
//   P[i=il(+16mf)][j = 16jf + 4g + rg].
// P -> PV B-frag via cvt_pk + permlane32_swap + permlane16_swap.
// defer-max (T13): skip m-update/rescale when __all(pmax <= m + 11.5) (exp2).
// LDS: 2 x 24KB K/V dbuf = 48KB -> 3 blocks/CU.
// ---------------------------------------------------------------------------
__global__ __launch_bounds__(256) void attn_mfma(
    const u16* __restrict__ Qh, const u16* __restrict__ Ql,
    const u16* __restrict__ Kh, const u16* __restrict__ Kl,
    const u16* __restrict__ Vh,
    u16* __restrict__ Oh, u16* __restrict__ Ol) {
  __shared__ char smem[49152];
  const int tid = threadIdx.x, lane = tid & 63, wv = tid >> 6;
  const int il = lane & 15, g = lane >> 4, x7 = il & 7;
  const int i0 = blockIdx.x * 128, h = blockIdx.y, b = blockIdx.z;
  const int iw = i0 + wv * 32;

  // Q fragments in registers: Q[i=16mf+il][d = 32ks + 8g + r]
  bf16x8 qh[2][2], ql[2][2];
  {
#pragma unroll
    for (int mf = 0; mf < 2; ++mf) {
      size_t rowq = ((size_t)b * NL + iw + 16 * mf + il) * ND + h * NDH + g * 8;
#pragma unroll
      for (int ks = 0; ks < 2; ++ks) {
        qh[mf][ks] = *(const bf16x8*)(Qh + rowq + ks * 32);
        ql[mf][ks] = *(const bf16x8*)(Ql + rowq + ks * 32);
      }
    }
  }

  // staging: tiles 64 rows x 128B, slot XOR (r&7)
  const int r0 = tid >> 3;
  const int swz0 = ((tid & 7) ^ (r0 & 7)) << 4;
  const char* gKh = (const char*)(Kh + ((size_t)b * NL + r0) * ND + h * NDH) + swz0;
  const char* gKl = (const char*)(Kl + ((size_t)b * NL + r0) * ND + h * NDH) + swz0;
  const char* gVh = (const char*)(Vh + ((size_t)b * ND + h * NDH + r0) * NL) + swz0;
  const int RSK = 32 * ND * 2, RSV = 32 * NL * 2;
  const int BUF = 24576;

  auto stage = [&](char* bb, int jt) {
    char* d = bb + wv * 1024;
    int ka = jt * (64 * ND * 2);
    int va = jt * 128;
    gll16(gKh + ka, d);
    gll16(gKh + ka + RSK, d + 4096);
    gll16(gKl + ka, d + 8192);
    gll16(gKl + ka + RSK, d + 12288);
    gll16(gVh + va, d + 16384);
    gll16(gVh + va + RSV, d + 20480);
  };

  int slotb[2];
#pragma unroll
  for (int ks = 0; ks < 2; ++ks) slotb[ks] = (((ks << 2) + g) ^ x7) << 4;
  const int frow = il * 128;

  f32x4 ot[4][2];
  float mrow[2], lrow[2];
#pragma unroll
  for (int df = 0; df < 4; ++df)
#pragma unroll
    for (int mf = 0; mf < 2; ++mf) ot[df][mf] = 0.0f;
  mrow[0] = mrow[1] = -INFINITY;
  lrow[0] = lrow[1] = 0.0f;

  stage(smem, 0);
  int cur = 0;
  for (int jt = 0; jt < NL / 64; ++jt) {
    __syncthreads();
    if (jt + 1 < NL / 64) stage(smem + (cur ^ 1) * BUF, jt + 1);
    const char* sb = smem + cur * BUF;

    // S^T = K · Q^T  (3-MFMA split; scale folded into Q)
    f32x4 st[4][2];
#pragma unroll
    for (int jf = 0; jf < 4; ++jf)
#pragma unroll
      for (int mf = 0; mf < 2; ++mf) st[jf][mf] = 0.0f;
#pragma unroll
    for (int ks = 0; ks < 2; ++ks) {
#pragma unroll
      for (int jf = 0; jf < 4; ++jf) {
        int rb = jf * 2048 + frow + slotb[ks];
        bf16x8 kh = *(const bf16x8*)(sb + rb);
        bf16x8 kl = *(const bf16x8*)(sb + 8192 + rb);
        __builtin_amdgcn_s_setprio(1);
#pragma unroll
        for (int mf = 0; mf < 2; ++mf) {
          st[jf][mf] = MFMA16(kh, qh[mf][ks], st[jf][mf], 0, 0, 0);
          st[jf][mf] = MFMA16(kl, qh[mf][ks], st[jf][mf], 0, 0, 0);
          st[jf][mf] = MFMA16(kh, ql[mf][ks], st[jf][mf], 0, 0, 0);
        }
        __builtin_amdgcn_s_setprio(0);
      }
    }

    // per-query tile max (rows lane-local; reduce over g via shfl 16/32)
    float mx2[2];
#pragma unroll
    for (int mf = 0; mf < 2; ++mf) {
      float mx = -INFINITY;
#pragma unroll
      for (int jf = 0; jf < 4; ++jf) {
        float a = fmaxf(st[jf][mf][0], st[jf][mf][1]);
        float c = fmaxf(st[jf][mf][2], st[jf][mf][3]);
        mx = fmaxf(mx, fmaxf(a, c));
      }
      mx = fmaxf(mx, __shfl_xor(mx, 16));
      mx = fmaxf(mx, __shfl_xor(mx, 32));
      mx2[mf] = mx;
    }
    // defer-max: skip rescale when tile max doesn't push m by > 11.5 (exp2 units)
    const int defer =
        __all((mx2[0] <= mrow[0] + 11.5f) && (mx2[1] <= mrow[1] + 11.5f));

    bf16x8 pfrag[2][2];
#pragma unroll
    for (int mf = 0; mf < 2; ++mf) {
      if (!defer) {
        float mn = fmaxf(mrow[mf], mx2[mf]);
        float al = __builtin_amdgcn_exp2f(mrow[mf] - mn);
        mrow[mf] = mn;
        lrow[mf] *= al;
#pragma unroll
        for (int df = 0; df < 4; ++df)
#pragma unroll
          for (int rg = 0; rg < 4; ++rg) ot[df][mf][rg] *= al;
      }
      const float mn = mrow[mf];
      float sum = 0.0f;
      unsigned pk[4][2];
#pragma unroll
      for (int jf = 0; jf < 4; ++jf) {
        float p0 = __builtin_amdgcn_exp2f(st[jf][mf][0] - mn);
        float p1 = __builtin_amdgcn_exp2f(st[jf][mf][1] - mn);
        float p2 = __builtin_amdgcn_exp2f(st[jf][mf][2] - mn);
        float p3 = __builtin_amdgcn_exp2f(st[jf][mf][3] - mn);
        sum += (p0 + p1) + (p2 + p3);
        pk[jf][0] = cvt_pk_bf16(p0, p1);
        pk[jf][1] = cvt_pk_bf16(p2, p3);
      }
      sum += __shfl_xor(sum, 16);
      sum += __shfl_xor(sum, 32);
      lrow[mf] += sum;

      // register redistribution -> PV B-fragments
#pragma unroll
      for (int ks = 0; ks < 2; ++ks) {
        unsigned u0, u1, u2, u3;
        {
          unsigned a = pk[2 * ks][0], bb2 = pk[2 * ks + 1][0];
          asm volatile("v_permlane32_swap_b32 %0, %1" : "+v"(a), "+v"(bb2));
          asm volatile("v_permlane16_swap_b32 %0, %1" : "+v"(a), "+v"(bb2));
          u0 = a; u2 = bb2;
        }
        {
          unsigned a = pk[2 * ks][1], bb2 = pk[2 * ks + 1][1];
          asm volatile("v_permlane32_swap_b32 %0, %1" : "+v"(a), "+v"(bb2));
          asm volatile("v_permlane16_swap_b32 %0, %1" : "+v"(a), "+v"(bb2));
          u1 = a; u3 = bb2;
        }
        union { unsigned w[4]; bf16x8 v; } cv;
        cv.w[0] = u0; cv.w[1] = u1; cv.w[2] = u2; cv.w[3] = u3;
        pfrag[mf][ks] = cv.v;
      }
    }

    // O^T += V · P^T
#pragma unroll
    for (int ks = 0; ks < 2; ++ks) {
#pragma unroll
      for (int df = 0; df < 4; ++df) {
        bf16x8 vh = *(const bf16x8*)(sb + 16384 + df * 2048 + frow + slotb[ks]);
        __builtin_amdgcn_s_setprio(1);
        ot[df][0] = MFMA16(vh, pfrag[0][ks], ot[df][0], 0, 0, 0);
        ot[df][1] = MFMA16(vh, pfrag[1][ks], ot[df][1], 0, 0, 0);
        __builtin_amdgcn_s_setprio(0);
      }
    }
    cur ^= 1;
  }

  // epilogue: O^T[d][i] -> bf16 hi/lo transposed [b][l=i][o=h*64+d]
#pragma unroll
  for (int mf = 0; mf < 2; ++mf) {
    float linv = 1.0f / lrow[mf];
    size_t orow = ((size_t)b * NL + iw + 16 * mf + il) * ND + h * NDH;
#pragma unroll
    for (int df = 0; df < 4; ++df) {
      u16x4 hh, ll;
#pragma unroll
      for (int rg = 0; rg < 4; ++rg) {
        float v = ot[df][mf][rg] * linv;
        hh[rg] = bf16_rne(v);
        ll[rg] = bf16_rne(v - bf16_to_f(hh[rg]));
      }
      *(u16x4*)(Oh + orow + df * 16 + g * 4) = hh;
      *(u16x4*)(Ol + orow + df * 16 + g * 4) = ll;
    }
  }
}

// ---------------------------------------------------------------------------
extern "C" void kernel_launch(void* const* d_in, const int* in_sizes, int n_in,
                              void* d_out, int out_size, void* d_ws, size_t ws_size,
                              hipStream_t stream) {
  const float* x = (const float*)d_in[0];
  const float* wq = (const float*)d_in[1];
  const float* wk = (const float*)d_in[2];
  const float* wv = (const float*)d_in[3];
  const float* wo = (const float*)d_in[4];
  const float* bo = (const float*)d_in[5];
  float* out = (float*)d_out;

  const size_t EL = (size_t)NB * ND * NL;  // 8Mi
  char* p = (char*)d_ws;
  u16* Xt_hi = (u16*)p; p += EL * 2;   // f16
  u16* Xt_lo = (u16*)p; p += EL * 2;   // f16
  u16* Qt_hi = (u16*)p; p += EL * 2;   // bf16
  u16* Qt_lo = (u16*)p; p += EL * 2;   // bf16
  u16* Kt_hi = (u16*)p; p += EL * 2;   // bf16
  u16* Kt_lo = (u16*)p; p += EL * 2;   // bf16
  u16* Vn_hi = (u16*)p; p += EL * 2;   // bf16
  u16* Vn_lo = (u16*)p; p += EL * 2;   // unused (layout parity with round 4)
  const size_t WE = (size_t)ND * ND;
  u16 *Wh[4], *Wl[4];
  for (int i = 0; i < 4; ++i) {
    Wh[i] = (u16*)p; p += WE * 2;
    Wl[i] = (u16*)p; p += WE * 2;
  }
  u16* Ot_hi = Xt_hi;  // Xt dead after V projection -> reuse for O (bf16)
  u16* Ot_lo = Xt_lo;

  dim3 tpb(256);
  prep_x<<<dim3(NL / 64, ND / 64, NB), tpb, 0, stream>>>(x, Xt_hi, Xt_lo);
  prep_w_f16<<<dim3(WE / 1024), tpb, 0, stream>>>(wq, Wh[0]);
  prep_w_f16<<<dim3(WE / 1024), tpb, 0, stream>>>(wk, Wh[1]);
  prep_w_f16<<<dim3(WE / 1024), tpb, 0, stream>>>(wv, Wh[2]);
  prep_w_bf<<<dim3(WE / 1024), tpb, 0, stream>>>(wo, Wh[3], Wl[3]);

  dim3 gg(NL / 128, ND / 128, NB);
  // Q scale = log2(e)/8 : softmax runs in exp2 units
  gemm_split<1, 2><<<gg, tpb, 0, stream>>>(Wh[0], nullptr, Xt_hi, Xt_lo,
                                           nullptr, nullptr, Qt_hi, Qt_lo,
                                           0.125f * 1.44269504088896f);
  gemm_split<1, 2><<<gg, tpb, 0, stream>>>(Wh[1], nullptr, Xt_hi, Xt_lo,
                                           nullptr, nullptr, Kt_hi, Kt_lo, 1.0f);
  gemm_split<2, 2><<<gg, tpb, 0, stream>>>(Wh[2], nullptr, Xt_hi, Xt_lo,
                                           nullptr, nullptr, Vn_hi, nullptr, 1.0f);

  attn_mfma<<<dim3(NL / 128, NH, NB), tpb, 0, stream>>>(
      Qt_hi, Qt_lo, Kt_hi, Kt_lo, Vn_hi, Ot_hi, Ot_lo);

  gemm_split<0, 3><<<gg, tpb, 0, stream>>>(Wh[3], Wl[3], Ot_hi, Ot_lo, out, bo,
                                           nullptr, nullptr, 1.0f);
}

// Round 7
// 417.189 us; speedup vs baseline: 5.2036x; 1.0461x over previous
//
#include <hip/hip_runtime.h>
#include <math.h>

#define NB 4
#define ND 1024
#define NL 2048
#define NH 16
#define NDH 64

typedef float f4 __attribute__((ext_vector_type(4)));
typedef float f32x4 __attribute__((ext_vector_type(4)));
typedef short bf16x8 __attribute__((ext_vector_type(8)));
typedef _Float16 f16x8 __attribute__((ext_vector_type(8)));
typedef unsigned short u16;
typedef u16 u16x4 __attribute__((ext_vector_type(4)));

#define MFMA16 __builtin_amdgcn_mfma_f32_16x16x32_bf16
#define MFMA16F __builtin_amdgcn_mfma_f32_16x16x32_f16

__device__ __forceinline__ u16 bf16_rne(float f) {
  unsigned u = __float_as_uint(f);
  u += 0x7fffu + ((u >> 16) & 1u);
  return (u16)(u >> 16);
}
__device__ __forceinline__ float bf16_to_f(u16 h) {
  return __uint_as_float(((unsigned)h) << 16);
}
__device__ __forceinline__ u16 f16_bits(float f) {
  union { _Float16 h; u16 u; } t;
  t.h = (_Float16)f;
  return t.u;
}
__device__ __forceinline__ float f16_val(u16 b) {
  union { _Float16 h; u16 u; } t;
  t.u = b;
  return (float)t.h;
}
__device__ __forceinline__ unsigned cvt_pk_bf16(float a, float b) {
  unsigned r;
  asm("v_cvt_pk_bf16_f32 %0, %1, %2" : "=v"(r) : "v"(a), "v"(b));
  return r;
}
__device__ __forceinline__ void gll16(const void* g, void* l) {
  __builtin_amdgcn_global_load_lds(
      (const __attribute__((address_space(1))) void*)g,
      (__attribute__((address_space(3))) void*)l, 16, 0, 0);
}

// dtype-dispatched MFMA on raw 16B registers
template <int TERMS>
__device__ __forceinline__ f32x4 mma(bf16x8 a, bf16x8 b, f32x4 c) {
  if constexpr (TERMS == 2) {
    union { bf16x8 s; f16x8 h; } ua, ub;
    ua.s = a; ub.s = b;
    return MFMA16F(ua.h, ub.h, c, 0, 0, 0);
  } else {
    return MFMA16(a, b, c, 0, 0, 0);
  }
}

// ---------------------------------------------------------------------------
// Prepass: X [b][d][l] fp32 -> Xt hi/lo FP16 [b][l][d] (transpose via LDS)
// ---------------------------------------------------------------------------
__global__ __launch_bounds__(256) void prep_x(const float* __restrict__ X,
                                              u16* __restrict__ Xhi,
                                              u16* __restrict__ Xlo) {
  __shared__ float t[64][65];
  const int tid = threadIdx.x;
  const int l0 = blockIdx.x * 64, d0 = blockIdx.y * 64, b = blockIdx.z;
  const float* Xb = X + ((size_t)b * ND + d0) * NL + l0;
#pragma unroll
  for (int r = 0; r < 16; ++r) {
    int idx = tid + r * 256;
    int d = idx >> 6, l = idx & 63;
    t[d][l] = Xb[(size_t)d * NL + l];
  }
  __syncthreads();
#pragma unroll
  for (int r = 0; r < 16; ++r) {
    int idx = tid + r * 256;
    int li = idx >> 6, dd = idx & 63;
    float v = t[dd][li];
    u16 hh = f16_bits(v);
    size_t o = ((size_t)b * NL + l0 + li) * ND + d0 + dd;
    Xhi[o] = hh;
    Xlo[o] = f16_bits(v - f16_val(hh));
  }
}

// ---------------------------------------------------------------------------
// Prepass: W [o][d] fp32 -> single FP16 (for the 2-term GEMMs)
// ---------------------------------------------------------------------------
__global__ __launch_bounds__(256) void prep_w_f16(const float* __restrict__ W,
                                                  u16* __restrict__ Whi) {
  int i = blockIdx.x * 256 + threadIdx.x;
  f4 v = ((const f4*)W)[i];
  u16x4 h;
#pragma unroll
  for (int k = 0; k < 4; ++k) h[k] = f16_bits(v[k]);
  ((u16x4*)Whi)[i] = h;
}

// ---------------------------------------------------------------------------
// MFMA GEMM: C[b,o,l] = sum_d W[o,d] * X[b,l,d]   (X given l-major)
// 128x128 tile, BK=32, double-buffered LDS, global_load_lds(16B) staging.
// TERMS=3: bf16 A hi/lo + B hi/lo, 3 MFMAs.
// TERMS=2: fp16 A single + B hi/lo, 2 MFMAs.
// MODE 0: fp32 + bias out [b][o][l]
// MODE 1: bf16 hi (and lo if non-null) transposed out [b][l][o], with scale
// MODE 2: bf16 hi natural out [b][o][l]
// ---------------------------------------------------------------------------
template <int MODE, int TERMS>
__global__ __launch_bounds__(256) void gemm_split(
    const u16* __restrict__ Ahi, const u16* __restrict__ Alo,
    const u16* __restrict__ Bhi, const u16* __restrict__ Blo,
    float* __restrict__ Cf, const float* __restrict__ bias,
    u16* __restrict__ Chi, u16* __restrict__ Clo, float scale) {
  constexpr int BUFSZ = (TERMS == 3) ? 32768 : 24576;
  constexpr int BH_OFF = (TERMS == 3) ? 16384 : 8192;
  constexpr int BL_OFF = (TERMS == 3) ? 24576 : 16384;
  __shared__ char smem[2 * BUFSZ];
  const int tid = threadIdx.x;
  const int lane = tid & 63, wv = tid >> 6;
  const int l0 = blockIdx.x * 128, o0 = blockIdx.y * 128, b = blockIdx.z;
  const int wo = (wv >> 1) * 64, wl = (wv & 1) * 64;

  // staging source map (inverse of phys layout); issue q adds 64 rows
  const int pr = tid >> 3;
  const int e = (tid & 7) ^ (pr & 7);
  const int r_src = pr * 2 + (e >> 2);
  const int s_src = e & 3;
  const char* gAh = (const char*)(Ahi + (size_t)(o0 + r_src) * ND) + s_src * 16;
  const char* gAl = (const char*)(Alo + (size_t)(o0 + r_src) * ND) + s_src * 16;
  const char* gBh = (const char*)(Bhi + ((size_t)b * NL + l0 + r_src) * ND) + s_src * 16;
  const char* gBl = (const char*)(Blo + ((size_t)b * NL + l0 + r_src) * ND) + s_src * 16;
  const int QROW = 64 * ND * 2;

  // fragment read offsets (per-lane constant swizzle)
  const int fswz = ((((lane & 1) << 2) | (lane >> 4)) ^ ((lane >> 1) & 7)) << 4;
  int offA[4], offB[4];
#pragma unroll
  for (int f = 0; f < 4; ++f) {
    offA[f] = ((wo + 16 * f + (lane & 15)) >> 1) * 128 + fswz;
    offB[f] = ((wl + 16 * f + (lane & 15)) >> 1) * 128 + fswz;
  }

  f32x4 acc[4][4];
#pragma unroll
  for (int mf = 0; mf < 4; ++mf)
#pragma unroll
    for (int nf = 0; nf < 4; ++nf) acc[mf][nf] = 0.0f;

  auto stage = [&](char* bb, int kbyte) {
    char* d = bb + wv * 1024;
    gll16(gAh + kbyte, d);
    gll16(gAh + kbyte + QROW, d + 4096);
    if constexpr (TERMS == 3) {
      gll16(gAl + kbyte, d + 8192);
      gll16(gAl + kbyte + QROW, d + 12288);
    }
    gll16(gBh + kbyte, d + BH_OFF);
    gll16(gBh + kbyte + QROW, d + BH_OFF + 4096);
    gll16(gBl + kbyte, d + BL_OFF);
    gll16(gBl + kbyte + QROW, d + BL_OFF + 4096);
  };

  stage(smem, 0);
  int cur = 0;
  for (int ks = 0; ks < ND / 32; ++ks) {
    __syncthreads();
    if (ks + 1 < ND / 32) stage(smem + (cur ^ 1) * BUFSZ, (ks + 1) * 64);
    const char* sb = smem + cur * BUFSZ;
    bf16x8 ah[4], al[4], bh[4], bl[4];
#pragma unroll
    for (int f = 0; f < 4; ++f) {
      ah[f] = *(const bf16x8*)(sb + offA[f]);
      if constexpr (TERMS == 3) al[f] = *(const bf16x8*)(sb + 8192 + offA[f]);
      bh[f] = *(const bf16x8*)(sb + BH_OFF + offB[f]);
      bl[f] = *(const bf16x8*)(sb + BL_OFF + offB[f]);
    }
    __builtin_amdgcn_s_setprio(1);
#pragma unroll
    for (int mf = 0; mf < 4; ++mf)
#pragma unroll
      for (int nf = 0; nf < 4; ++nf) {
        acc[mf][nf] = mma<TERMS>(ah[mf], bh[nf], acc[mf][nf]);
        acc[mf][nf] = mma<TERMS>(ah[mf], bl[nf], acc[mf][nf]);
        if constexpr (TERMS == 3)
          acc[mf][nf] = mma<TERMS>(al[mf], bh[nf], acc[mf][nf]);
      }
    __builtin_amdgcn_s_setprio(0);
    cur ^= 1;
  }

  const int col = lane & 15, row4 = (lane >> 4) * 4;
  if constexpr (MODE == 0) {
    const size_t cb = (size_t)b * ND * NL;
#pragma unroll
    for (int mf = 0; mf < 4; ++mf)
#pragma unroll
      for (int rg = 0; rg < 4; ++rg) {
        int o = o0 + wo + 16 * mf + row4 + rg;
        float bv = bias[o];
        float* crow = Cf + cb + (size_t)o * NL + l0 + wl + col;
#pragma unroll
        for (int nf = 0; nf < 4; ++nf) crow[16 * nf] = acc[mf][nf][rg] + bv;
      }
  } else if constexpr (MODE == 1) {
#pragma unroll
    for (int nf = 0; nf < 4; ++nf) {
      size_t lrow = ((size_t)b * NL + l0 + wl + 16 * nf + col) * ND + o0 + wo;
#pragma unroll
      for (int mf = 0; mf < 4; ++mf) {
        u16x4 h, l;
#pragma unroll
        for (int rg = 0; rg < 4; ++rg) {
          float v = acc[mf][nf][rg] * scale;
          h[rg] = bf16_rne(v);
          l[rg] = bf16_rne(v - bf16_to_f(h[rg]));
        }
        *(u16x4*)(Chi + lrow + 16 * mf + row4) = h;
        if (Clo) *(u16x4*)(Clo + lrow + 16 * mf + row4) = l;
      }
    }
  } else {
    const size_t cb = (size_t)b * ND * NL;
#pragma unroll
    for (int mf = 0; mf < 4; ++mf)
#pragma unroll
      for (int rg = 0; rg < 4; ++rg) {
        int o = o0 + wo + 16 * mf + row4 + rg;
        u16* hrow = Chi + cb + (size_t)o * NL + l0 + wl + col;
#pragma unroll
        for (int nf = 0; nf < 4; ++nf) {
          float v = acc[mf][nf][rg];
          hrow[16 * nf] = bf16_rne(v);
        }
      }
  }
}

// ---------------------------------------------------------------------------
// Flash attention — round-4 structure, bf16 throughout, minimal diff:
//   * K is bf16 SINGLE (hi only): QK^T = kh*qh + kh*ql (2 MFMAs; dropped
//     kl*qh term adds ~1.6e-3 exp2-units error, within budget).
//   * LDS buffer = Kh 8KB + V 8KB = 16KB; dbuf 32KB -> 5 blocks/CU.
//   * Epilogue emits O as FP16 hi/lo (feeds the 2-term fp16 WO GEMM).
// Everything else (layouts, swizzles, P-in-register permlane path, defer-max)
// is byte-identical to the round-4/6 kernel.
// ---------------------------------------------------------------------------
__global__ __launch_bounds__(256) void attn_mfma(
    const u16* __restrict__ Qh, const u16* __restrict__ Ql,
    const u16* __restrict__ Kh, const u16* __restrict__ Vh,
    u16* __restrict__ Oh, u16* __restrict__ Ol) {
  __shared__ char smem[32768];
  const int tid = threadIdx.x, lane = tid & 63, wv = tid >> 6;
  const int il = lane & 15, g = lane >> 4, x7 = il & 7;
  const int i0 = blockIdx.x * 128, h = blockIdx.y, b = blockIdx.z;
  const int iw = i0 + wv * 32;

  // Q fragments in registers: Q[i=16mf+il][d = 32ks + 8g + r]
  bf16x8 qh[2][2], ql[2][2];
  {
#pragma unroll
    for (int mf = 0; mf < 2; ++mf) {
      size_t rowq = ((size_t)b * NL + iw + 16 * mf + il) * ND + h * NDH + g * 8;
#pragma unroll
      for (int ks = 0; ks < 2; ++ks) {
        qh[mf][ks] = *(const bf16x8*)(Qh + rowq + ks * 32);
        ql[mf][ks] = *(const bf16x8*)(Ql + rowq + ks * 32);
      }
    }
  }

  // staging: tiles 64 rows x 128B, slot XOR (r&7)
  const int r0 = tid >> 3;
  const int swz0 = ((tid & 7) ^ (r0 & 7)) << 4;
  const char* gKh = (const char*)(Kh + ((size_t)b * NL + r0) * ND + h * NDH) + swz0;
  const char* gVh = (const char*)(Vh + ((size_t)b * ND + h * NDH + r0) * NL) + swz0;
  const int RSK = 32 * ND * 2, RSV = 32 * NL * 2;
  const int BUF = 16384;

  auto stage = [&](char* bb, int jt) {
    char* d = bb + wv * 1024;
    int ka = jt * (64 * ND * 2);
    int va = jt * 128;
    gll16(gKh + ka, d);
    gll16(gKh + ka + RSK, d + 4096);
    gll16(gVh + va, d + 8192);
    gll16(gVh + va + RSV, d + 12288);
  };

  int slotb[2];
#pragma unroll
  for (int ks = 0; ks < 2; ++ks) slotb[ks] = (((ks << 2) + g) ^ x7) << 4;
  const int frow = il * 128;

  f32x4 ot[4][2];
  float mrow[2], lrow[2];
#pragma unroll
  for (int df = 0; df < 4; ++df)
#pragma unroll
    for (int mf = 0; mf < 2; ++mf) ot[df][mf] = 0.0f;
  mrow[0] = mrow[1] = -INFINITY;
  lrow[0] = lrow[1] = 0.0f;

  stage(smem, 0);
  int cur = 0;
  for (int jt = 0; jt < NL / 64; ++jt) {
    __syncthreads();
    if (jt + 1 < NL / 64) stage(smem + (cur ^ 1) * BUF, jt + 1);
    const char* sb = smem + cur * BUF;

    // S^T = K_hi · (Q_hi + Q_lo)^T  (2-MFMA; scale folded into Q)
    f32x4 st[4][2];
#pragma unroll
    for (int jf = 0; jf < 4; ++jf)
#pragma unroll
      for (int mf = 0; mf < 2; ++mf) st[jf][mf] = 0.0f;
#pragma unroll
    for (int ks = 0; ks < 2; ++ks) {
#pragma unroll
      for (int jf = 0; jf < 4; ++jf) {
        int rb = jf * 2048 + frow + slotb[ks];
        bf16x8 kh = *(const bf16x8*)(sb + rb);
        __builtin_amdgcn_s_setprio(1);
#pragma unroll
        for (int mf = 0; mf < 2; ++mf) {
          st[jf][mf] = MFMA16(kh, qh[mf][ks], st[jf][mf], 0, 0, 0);
          st[jf][mf] = MFMA16(kh, ql[mf][ks], st[jf][mf], 0, 0, 0);
        }
        __builtin_amdgcn_s_setprio(0);
      }
    }

    // per-query tile max (rows lane-local; reduce over g via shfl 16/32)
    float mx2[2];
#pragma unroll
    for (int mf = 0; mf < 2; ++mf) {
      float mx = -INFINITY;
#pragma unroll
      for (int jf = 0; jf < 4; ++jf) {
        float a = fmaxf(st[jf][mf][0], st[jf][mf][1]);
        float c = fmaxf(st[jf][mf][2], st[jf][mf][3]);
        mx = fmaxf(mx, fmaxf(a, c));
      }
      mx = fmaxf(mx, __shfl_xor(mx, 16));
      mx = fmaxf(mx, __shfl_xor(mx, 32));
      mx2[mf] = mx;
    }
    // defer-max: skip rescale when tile max doesn't push m by > 11.5 (exp2 units)
    const int defer =
        __all((mx2[0] <= mrow[0] + 11.5f) && (mx2[1] <= mrow[1] + 11.5f));

    bf16x8 pfrag[2][2];
#pragma unroll
    for (int mf = 0; mf < 2; ++mf) {
      if (!defer) {
        float mn = fmaxf(mrow[mf], mx2[mf]);
        float al = __builtin_amdgcn_exp2f(mrow[mf] - mn);
        mrow[mf] = mn;
        lrow[mf] *= al;
#pragma unroll
        for (int df = 0; df < 4; ++df)
#pragma unroll
          for (int rg = 0; rg < 4; ++rg) ot[df][mf][rg] *= al;
      }
      const float mn = mrow[mf];
      float sum = 0.0f;
      unsigned pk[4][2];
#pragma unroll
      for (int jf = 0; jf < 4; ++jf) {
        float p0 = __builtin_amdgcn_exp2f(st[jf][mf][0] - mn);
        float p1 = __builtin_amdgcn_exp2f(st[jf][mf][1] - mn);
        float p2 = __builtin_amdgcn_exp2f(st[jf][mf][2] - mn);
        float p3 = __builtin_amdgcn_exp2f(st[jf][mf][3] - mn);
        sum += (p0 + p1) + (p2 + p3);
        pk[jf][0] = cvt_pk_bf16(p0, p1);
        pk[jf][1] = cvt_pk_bf16(p2, p3);
      }
      sum += __shfl_xor(sum, 16);
      sum += __shfl_xor(sum, 32);
      lrow[mf] += sum;

      // register redistribution -> PV B-fragments
#pragma unroll
      for (int ks = 0; ks < 2; ++ks) {
        unsigned u0, u1, u2, u3;
        {
          unsigned a = pk[2 * ks][0], bb2 = pk[2 * ks + 1][0];
          asm volatile("v_permlane32_swap_b32 %0, %1" : "+v"(a), "+v"(bb2));
          asm volatile("v_permlane16_swap_b32 %0, %1" : "+v"(a), "+v"(bb2));
          u0 = a; u2 = bb2;
        }
        {
          unsigned a = pk[2 * ks][1], bb2 = pk[2 * ks + 1][1];
          asm volatile("v_permlane32_swap_b32 %0, %1" : "+v"(a), "+v"(bb2));
          asm volatile("v_permlane16_swap_b32 %0, %1" : "+v"(a), "+v"(bb2));
          u1 = a; u3 = bb2;
        }
        union { unsigned w[4]; bf16x8 v; } cv;
        cv.w[0] = u0; cv.w[1] = u1; cv.w[2] = u2; cv.w[3] = u3;
        pfrag[mf][ks] = cv.v;
      }
    }

    // O^T += V · P^T
#pragma unroll
    for (int ks = 0; ks < 2; ++ks) {
#pragma unroll
      for (int df = 0; df < 4; ++df) {
        bf16x8 vh = *(const bf16x8*)(sb + 8192 + df * 2048 + frow + slotb[ks]);
        __builtin_amdgcn_s_setprio(1);
        ot[df][0] = MFMA16(vh, pfrag[0][ks], ot[df][0], 0, 0, 0);
        ot[df][1] = MFMA16(vh, pfrag[1][ks], ot[df][1], 0, 0, 0);
        __builtin_amdgcn_s_setprio(0);
      }
    }
    cur ^= 1;
  }

  // epilogue: O^T[d][i] -> FP16 hi/lo transposed [b][l=i][o=h*64+d]
#pragma unroll
  for (int mf = 0; mf < 2; ++mf) {
    float linv = 1.0f / lrow[mf];
    size_t orow = ((size_t)b * NL + iw + 16 * mf + il) * ND + h * NDH;
#pragma unroll
    for (int df = 0; df < 4; ++df) {
      u16x4 hh, ll;
#pragma unroll
      for (int rg = 0; rg < 4; ++rg) {
        float v = ot[df][mf][rg] * linv;
        hh[rg] = f16_bits(v);
        ll[rg] = f16_bits(v - f16_val(hh[rg]));
      }
      *(u16x4*)(Oh + orow + df * 16 + g * 4) = hh;
      *(u16x4*)(Ol + orow + df * 16 + g * 4) = ll;
    }
  }
}

// ---------------------------------------------------------------------------
extern "C" void kernel_launch(void* const* d_in, const int* in_sizes, int n_in,
                              void* d_out, int out_size, void* d_ws, size_t ws_size,
                              hipStream_t stream) {
  const float* x = (const float*)d_in[0];
  const float* wq = (const float*)d_in[1];
  const float* wk = (const float*)d_in[2];
  const float* wv = (const float*)d_in[3];
  const float* wo = (const float*)d_in[4];
  const float* bo = (const float*)d_in[5];
  float* out = (float*)d_out;

  const size_t EL = (size_t)NB * ND * NL;  // 8Mi
  char* p = (char*)d_ws;
  u16* Xt_hi = (u16*)p; p += EL * 2;   // f16
  u16* Xt_lo = (u16*)p; p += EL * 2;   // f16
  u16* Qt_hi = (u16*)p; p += EL * 2;   // bf16
  u16* Qt_lo = (u16*)p; p += EL * 2;   // bf16
  u16* Kt_hi = (u16*)p; p += EL * 2;   // bf16 (single)
  u16* Kt_lo = (u16*)p; p += EL * 2;   // unused (layout parity)
  u16* Vn_hi = (u16*)p; p += EL * 2;   // bf16
  u16* Vn_lo = (u16*)p; p += EL * 2;   // unused (layout parity)
  const size_t WE = (size_t)ND * ND;
  u16 *Wh[4], *Wl[4];
  for (int i = 0; i < 4; ++i) {
    Wh[i] = (u16*)p; p += WE * 2;
    Wl[i] = (u16*)p; p += WE * 2;
  }
  u16* Ot_hi = Xt_hi;  // Xt dead after V projection -> reuse for O (f16)
  u16* Ot_lo = Xt_lo;

  dim3 tpb(256);
  prep_x<<<dim3(NL / 64, ND / 64, NB), tpb, 0, stream>>>(x, Xt_hi, Xt_lo);
  prep_w_f16<<<dim3(WE / 1024), tpb, 0, stream>>>(wq, Wh[0]);
  prep_w_f16<<<dim3(WE / 1024), tpb, 0, stream>>>(wk, Wh[1]);
  prep_w_f16<<<dim3(WE / 1024), tpb, 0, stream>>>(wv, Wh[2]);
  prep_w_f16<<<dim3(WE / 1024), tpb, 0, stream>>>(wo, Wh[3]);

  dim3 gg(NL / 128, ND / 128, NB);
  // Q scale = log2(e)/8 : softmax runs in exp2 units
  gemm_split<1, 2><<<gg, tpb, 0, stream>>>(Wh[0], nullptr, Xt_hi, Xt_lo,
                                           nullptr, nullptr, Qt_hi, Qt_lo,
                                           0.125f * 1.44269504088896f);
  // K -> bf16 single (hi only)
  gemm_split<1, 2><<<gg, tpb, 0, stream>>>(Wh[1], nullptr, Xt_hi, Xt_lo,
                                           nullptr, nullptr, Kt_hi, nullptr, 1.0f);
  gemm_split<2, 2><<<gg, tpb, 0, stream>>>(Wh[2], nullptr, Xt_hi, Xt_lo,
                                           nullptr, nullptr, Vn_hi, nullptr, 1.0f);

  attn_mfma<<<dim3(NL / 128, NH, NB), tpb, 0, stream>>>(
      Qt_hi, Qt_lo, Kt_hi, Vn_hi, Ot_hi, Ot_lo);

  // WO: fp16 single W x fp16 hi/lo O, 2-term
  gemm_split<0, 2><<<gg, tpb, 0, stream>>>(Wh[3], nullptr, Ot_hi, Ot_lo, out, bo,
                                           nullptr, nullptr, 1.0f);
}